// Round 2
// baseline (4145.990 us; speedup 1.0000x reference)
//
#include <hip/hip_runtime.h>
#include <cstdint>

// Problem constants (fixed by the reference)
#define NB   2
#define TSEQ 2048
#define NT   4096      // NB*TSEQ tokens
#define CDIM 1024
#define DDIM 128
#define FFDIM 2048
#define NE   8         // experts (both attn and moe)

// ---- workspace layout (bytes) ----
#define OFF_COUNTS_A 0            // 8 ints
#define OFF_COUNTS_M 64           // 8 ints
#define OFF_COLINV   128          // 16 floats (attn 0..7, moe 8..15)
#define OFF_W_A      1024                         // NT*NE f32
#define OFF_W_M      (OFF_W_A + NT*NE*4)
#define OFF_LIST_A   (OFF_W_M + NT*NE*4)          // NT*NE ints (8 lists of NT)
#define OFF_LIST_M   (OFF_LIST_A + NT*NE*4)
#define OFF_Q        (1<<20)
#define OFF_K        (OFF_Q + NT*DDIM*4)
#define OFF_V        (OFF_K + NT*DDIM*4)
#define OFF_AO       (OFF_V + NT*DDIM*4)
#define OFF_H        (OFF_AO + NT*DDIM*4)
#define OFF_ABUF     (OFF_H + NT*CDIM*4)          // NT*FFDIM f32 (per-expert reuse)
// total ≈ 59.8 MB

__device__ __forceinline__ float gelu_tanh(float x) {
    float x3 = x*x*x;
    return 0.5f*x*(1.0f + tanhf(0.79788456080286535588f*(x + 0.044715f*x3)));
}

// ---------------- column norms of sim matrices ----------------
__global__ void colnorm_kernel(const float* __restrict__ asim,
                               const float* __restrict__ msim,
                               float* __restrict__ inv) {
    int col = blockIdx.x;                 // 0..15
    const float* s = (col < NE) ? asim : msim;
    int e = col & (NE-1);
    int tid = threadIdx.x;
    float ss = 0.0f;
    for (int c = tid; c < CDIM; c += 256) { float v = s[(size_t)c*NE + e]; ss += v*v; }
    __shared__ float red[256];
    red[tid] = ss; __syncthreads();
    for (int st = 128; st > 0; st >>= 1) { if (tid < st) red[tid] += red[tid+st]; __syncthreads(); }
    if (tid == 0) inv[col] = 1.0f / fmaxf(sqrtf(red[0]), 1e-12f);
}

// ---------------- gating (shared for attn / moe) ----------------
__global__ void gating_kernel(const float* __restrict__ xin,
                              const float* __restrict__ sim,
                              const float* __restrict__ gates,
                              const float* __restrict__ colinv,
                              const int* __restrict__ kmin_p,
                              float* __restrict__ wout,
                              int* __restrict__ counts,
                              int* __restrict__ lists) {
    const int n = blockIdx.x, tid = threadIdx.x;
    const float* xr = xin + (size_t)n*CDIM;
    float4 xv = *(const float4*)(xr + tid*4);
    float acc[9];
    acc[0] = xv.x*xv.x + xv.y*xv.y + xv.z*xv.z + xv.w*xv.w;
    int c = tid*4;
    #pragma unroll
    for (int e = 0; e < NE; e++)
        acc[1+e] = xv.x*sim[(size_t)(c+0)*NE+e] + xv.y*sim[(size_t)(c+1)*NE+e]
                 + xv.z*sim[(size_t)(c+2)*NE+e] + xv.w*sim[(size_t)(c+3)*NE+e];
    __shared__ float red[9][256];
    #pragma unroll
    for (int a = 0; a < 9; a++) red[a][tid] = acc[a];
    __syncthreads();
    for (int s = 128; s > 0; s >>= 1) {
        if (tid < s) {
            #pragma unroll
            for (int a = 0; a < 9; a++) red[a][tid] += red[a][tid+s];
        }
        __syncthreads();
    }
    if (tid == 0) {
        float xinv = 1.0f / fmaxf(sqrtf(red[0][0]), 1e-12f);
        float logits[NE], gated[NE];
        int mask[NE]; int any = 0;
        #pragma unroll
        for (int e = 0; e < NE; e++) {
            float lg = red[1+e][0]*xinv*colinv[e] - 1.0f/(1.0f + expf(-gates[e]));
            logits[e] = lg; gated[e] = fmaxf(lg, 0.0f);
            mask[e] = (lg > 0.0f) ? 1 : 0; any |= mask[e];
        }
        if (!any) {   // fallback: top-kmin by logits (ties -> lowest index)
            int kmin = *kmin_p; if (kmin < 1) kmin = 1; if (kmin > NE) kmin = NE;
            int used[NE] = {0,0,0,0,0,0,0,0};
            for (int kk = 0; kk < kmin; kk++) {
                int best = -1; float bv = 0.0f;
                for (int e = 0; e < NE; e++)
                    if (!used[e] && (best < 0 || logits[e] > bv)) { best = e; bv = logits[e]; }
                used[best] = 1; mask[best] = 1;
            }
        }
        float mx = -3.402823466e38f;
        #pragma unroll
        for (int e = 0; e < NE; e++) { float me = mask[e] ? gated[e] : -1.0e9f; mx = fmaxf(mx, me); }
        float sum = 0.0f, p[NE];
        #pragma unroll
        for (int e = 0; e < NE; e++) { p[e] = expf((mask[e] ? gated[e] : -1.0e9f) - mx); sum += p[e]; }
        float sinv = 1.0f / sum;
        #pragma unroll
        for (int e = 0; e < NE; e++) {
            float w = mask[e] ? p[e]*sinv : 0.0f;
            wout[(size_t)n*NE + e] = w;
            if (mask[e]) { int pos = atomicAdd(&counts[e], 1); lists[e*NT + pos] = n; }
        }
    }
}

// ---------------- grouped GEMM: QKV projections ----------------
// grid (64 tiles, 6 out-chunks, 8 experts), 256 thr, tile 64 tok x 64 out, K=1024
__global__ __launch_bounds__(256) void qkv_kernel(
        const float* __restrict__ x,
        const float* __restrict__ qw, const float* __restrict__ kw, const float* __restrict__ vw,
        const float* __restrict__ wgt, const int* __restrict__ counts, const int* __restrict__ lists,
        float* __restrict__ qo, float* __restrict__ ko, float* __restrict__ vo) {
    const int e = blockIdx.z;
    const int cnt = counts[e];
    const int tile = blockIdx.x;
    if (tile*64 >= cnt) return;
    const int oc = blockIdx.y;  // 0..5 : q0,q1,k0,k1,v0,v1
    const float* W = (oc < 2 ? qw : (oc < 4 ? kw : vw)) + (size_t)e*CDIM*DDIM + (oc & 1)*64;
    float* dst = (oc < 2 ? qo : (oc < 4 ? ko : vo)) + (oc & 1)*64;
    __shared__ float As[16][68];
    __shared__ float Bs[16][68];
    __shared__ int   toks[64];
    __shared__ float wro[64];
    const int tid = threadIdx.x;
    if (tid < 64) {
        int rid = tile*64 + tid;
        int t = lists[e*NT + (rid < cnt ? rid : cnt-1)];
        toks[tid] = t; wro[tid] = wgt[(size_t)t*NE + e];
    }
    __syncthreads();
    const int tx = tid & 15, ty = tid >> 4;
    const int ltok = tid >> 2, lk = (tid & 3)*4;
    const int bk = tid >> 4, bn = (tid & 15)*4;
    const float* xrow = x + (size_t)toks[ltok]*CDIM;
    float acc[4][4] = {};
    for (int kc = 0; kc < CDIM; kc += 16) {
        float4 av = *(const float4*)(xrow + kc + lk);
        float4 bv = *(const float4*)(W + (size_t)(kc + bk)*DDIM + bn);
        As[lk+0][ltok] = av.x; As[lk+1][ltok] = av.y; As[lk+2][ltok] = av.z; As[lk+3][ltok] = av.w;
        *(float4*)&Bs[bk][bn] = bv;
        __syncthreads();
        #pragma unroll
        for (int kk = 0; kk < 16; kk++) {
            float4 a4 = *(const float4*)&As[kk][ty*4];
            float4 b4 = *(const float4*)&Bs[kk][tx*4];
            float a_[4] = {a4.x, a4.y, a4.z, a4.w};
            float b_[4] = {b4.x, b4.y, b4.z, b4.w};
            #pragma unroll
            for (int i = 0; i < 4; i++)
                #pragma unroll
                for (int j = 0; j < 4; j++) acc[i][j] += a_[i]*b_[j];
        }
        __syncthreads();
    }
    #pragma unroll
    for (int i = 0; i < 4; i++) {
        int row = ty*4 + i;
        if (tile*64 + row < cnt) {
            int t = toks[row]; float wv = wro[row];
            #pragma unroll
            for (int j = 0; j < 4; j++)
                atomicAdd(&dst[(size_t)t*DDIM + tx*4 + j], acc[i][j]*wv);
        }
    }
}

// ---------------- RoPE on q,k in place ----------------
__global__ void rope_kernel(float* __restrict__ q, float* __restrict__ k,
                            const int* __restrict__ pos_ids) {
    int n = blockIdx.x, j = threadIdx.x;   // j in 0..63
    float pos = (float)pos_ids[n];
    float inv = expf(-((float)j / 64.0f) * 9.21034037197618274f);  // 10000^(-j/64)
    float ang = pos * inv;
    float c = cosf(ang), s = sinf(ang);
    float* qr = q + (size_t)n*DDIM;
    float* kr = k + (size_t)n*DDIM;
    float q0 = qr[j], q1 = qr[j+64];
    qr[j]    = q0*c - q1*s;
    qr[j+64] = q1*c + q0*s;
    float k0 = kr[j], k1 = kr[j+64];
    kr[j]    = k0*c - k1*s;
    kr[j+64] = k1*c + k0*s;
}

// ---------------- flash attention, fp32, causal ----------------
// grid (T/64, B), 256 thr. Q tile 64 rows, KV tile 32. Thread (r=tid>>2, qq=tid&3)
// owns q-row r, dims {qq+4m}. Full dots via shfl_xor over the 4-lane group.
__global__ __launch_bounds__(256) void attn_kernel(
        const float* __restrict__ q, const float* __restrict__ kbuf,
        const float* __restrict__ vbuf, float* __restrict__ o) {
    const int b = blockIdx.y, qt = blockIdx.x;
    const int tid = threadIdx.x;
    const int r = tid >> 2, qq = tid & 3;
    const int qrow = qt*64 + r;
    const float scale = 0.08838834764831845f;   // 1/sqrt(128)
    __shared__ float Ks[32][132];
    __shared__ float Vs[32][132];
    float qreg[32];
    const float* qr_ = q + ((size_t)b*TSEQ + qrow)*DDIM;
    #pragma unroll
    for (int m = 0; m < 32; m++) qreg[m] = qr_[qq + 4*m] * scale;
    float Oacc[32] = {};
    float mrun = -INFINITY, lrun = 0.0f;
    const int ntiles = qt*2 + 2;
    for (int kt = 0; kt < ntiles; kt++) {
        const int kvbase = kt*32;
        for (int i = tid; i < 1024; i += 256) {
            int row = i >> 5, c4 = i & 31;
            *(float4*)&Ks[row][c4*4] = *(const float4*)&kbuf[((size_t)b*TSEQ + kvbase + row)*DDIM + c4*4];
            *(float4*)&Vs[row][c4*4] = *(const float4*)&vbuf[((size_t)b*TSEQ + kvbase + row)*DDIM + c4*4];
        }
        __syncthreads();
        float s[32];
        #pragma unroll
        for (int cc = 0; cc < 32; cc++) {
            float a = 0.0f;
            #pragma unroll
            for (int m = 0; m < 32; m++) a += qreg[m]*Ks[cc][qq + 4*m];
            s[cc] = a;
        }
        #pragma unroll
        for (int cc = 0; cc < 32; cc++) {
            s[cc] += __shfl_xor(s[cc], 1);
            s[cc] += __shfl_xor(s[cc], 2);
        }
        float mloc = -INFINITY;
        #pragma unroll
        for (int cc = 0; cc < 32; cc++) {
            if (kvbase + cc > qrow) s[cc] = -3.402823466e38f;
            mloc = fmaxf(mloc, s[cc]);
        }
        float mnew = fmaxf(mrun, mloc);
        float alpha = expf(mrun - mnew);
        float lsum = 0.0f;
        #pragma unroll
        for (int cc = 0; cc < 32; cc++) { s[cc] = expf(s[cc] - mnew); lsum += s[cc]; }
        lrun = lrun*alpha + lsum;
        mrun = mnew;
        #pragma unroll
        for (int m = 0; m < 32; m++) Oacc[m] *= alpha;
        #pragma unroll
        for (int cc = 0; cc < 32; cc++) {
            float pc = s[cc];
            #pragma unroll
            for (int m = 0; m < 32; m++) Oacc[m] += pc * Vs[cc][qq + 4*m];
        }
        __syncthreads();
    }
    float linv = 1.0f / lrun;
    float* orow = o + ((size_t)b*TSEQ + qrow)*DDIM;
    #pragma unroll
    for (int m = 0; m < 32; m++) orow[qq + 4*m] = Oacc[m]*linv;
}

// ---------------- grouped GEMM: o_proj (+ atomic into h) ----------------
// grid (64, 16, 8), K=128, W = o_proj[e] [128][1024]
__global__ __launch_bounds__(256) void oproj_kernel(
        const float* __restrict__ ao, const float* __restrict__ ow,
        const float* __restrict__ wgt, const int* __restrict__ counts,
        const int* __restrict__ lists, float* __restrict__ h) {
    const int e = blockIdx.z;
    const int cnt = counts[e];
    const int tile = blockIdx.x;
    if (tile*64 >= cnt) return;
    const int cbase = blockIdx.y*64;
    const float* W = ow + (size_t)e*DDIM*CDIM + cbase;
    __shared__ float As[16][68];
    __shared__ float Bs[16][68];
    __shared__ int   toks[64];
    __shared__ float wro[64];
    const int tid = threadIdx.x;
    if (tid < 64) {
        int rid = tile*64 + tid;
        int t = lists[e*NT + (rid < cnt ? rid : cnt-1)];
        toks[tid] = t; wro[tid] = wgt[(size_t)t*NE + e];
    }
    __syncthreads();
    const int tx = tid & 15, ty = tid >> 4;
    const int ltok = tid >> 2, lk = (tid & 3)*4;
    const int bk = tid >> 4, bn = (tid & 15)*4;
    const float* arow = ao + (size_t)toks[ltok]*DDIM;
    float acc[4][4] = {};
    for (int kc = 0; kc < DDIM; kc += 16) {
        float4 av = *(const float4*)(arow + kc + lk);
        float4 bv = *(const float4*)(W + (size_t)(kc + bk)*CDIM + bn);
        As[lk+0][ltok] = av.x; As[lk+1][ltok] = av.y; As[lk+2][ltok] = av.z; As[lk+3][ltok] = av.w;
        *(float4*)&Bs[bk][bn] = bv;
        __syncthreads();
        #pragma unroll
        for (int kk = 0; kk < 16; kk++) {
            float4 a4 = *(const float4*)&As[kk][ty*4];
            float4 b4 = *(const float4*)&Bs[kk][tx*4];
            float a_[4] = {a4.x, a4.y, a4.z, a4.w};
            float b_[4] = {b4.x, b4.y, b4.z, b4.w};
            #pragma unroll
            for (int i = 0; i < 4; i++)
                #pragma unroll
                for (int j = 0; j < 4; j++) acc[i][j] += a_[i]*b_[j];
        }
        __syncthreads();
    }
    #pragma unroll
    for (int i = 0; i < 4; i++) {
        int row = ty*4 + i;
        if (tile*64 + row < cnt) {
            int t = toks[row]; float wv = wro[row];
            #pragma unroll
            for (int j = 0; j < 4; j++)
                atomicAdd(&h[(size_t)t*CDIM + cbase + tx*4 + j], acc[i][j]*wv);
        }
    }
}

// ---------------- MoE stage 1: A = gelu(h @ W1e), per expert ----------------
// grid (64, 32), K=1024, W1e [1024][2048]
__global__ __launch_bounds__(256) void moe1_kernel(
        const float* __restrict__ h, const float* __restrict__ w1,
        const int* __restrict__ counts, const int* __restrict__ lists,
        float* __restrict__ A, int e) {
    const int cnt = counts[e];
    const int tile = blockIdx.x;
    if (tile*64 >= cnt) return;
    const int fbase = blockIdx.y*64;
    const float* W = w1 + (size_t)e*CDIM*FFDIM + fbase;
    __shared__ float As[16][68];
    __shared__ float Bs[16][68];
    __shared__ int toks[64];
    const int tid = threadIdx.x;
    if (tid < 64) {
        int rid = tile*64 + tid;
        toks[tid] = lists[e*NT + (rid < cnt ? rid : cnt-1)];
    }
    __syncthreads();
    const int tx = tid & 15, ty = tid >> 4;
    const int ltok = tid >> 2, lk = (tid & 3)*4;
    const int bk = tid >> 4, bn = (tid & 15)*4;
    const float* hrow = h + (size_t)toks[ltok]*CDIM;
    float acc[4][4] = {};
    for (int kc = 0; kc < CDIM; kc += 16) {
        float4 av = *(const float4*)(hrow + kc + lk);
        float4 bv = *(const float4*)(W + (size_t)(kc + bk)*FFDIM + bn);
        As[lk+0][ltok] = av.x; As[lk+1][ltok] = av.y; As[lk+2][ltok] = av.z; As[lk+3][ltok] = av.w;
        *(float4*)&Bs[bk][bn] = bv;
        __syncthreads();
        #pragma unroll
        for (int kk = 0; kk < 16; kk++) {
            float4 a4 = *(const float4*)&As[kk][ty*4];
            float4 b4 = *(const float4*)&Bs[kk][tx*4];
            float a_[4] = {a4.x, a4.y, a4.z, a4.w};
            float b_[4] = {b4.x, b4.y, b4.z, b4.w};
            #pragma unroll
            for (int i = 0; i < 4; i++)
                #pragma unroll
                for (int j = 0; j < 4; j++) acc[i][j] += a_[i]*b_[j];
        }
        __syncthreads();
    }
    #pragma unroll
    for (int i = 0; i < 4; i++) {
        int row = ty*4 + i;
        if (tile*64 + row < cnt) {
            #pragma unroll
            for (int j = 0; j < 4; j++)
                A[(size_t)(tile*64 + row)*FFDIM + fbase + tx*4 + j] = gelu_tanh(acc[i][j]);
        }
    }
}

// ---------------- MoE stage 2: out += w * (A @ W2e), per expert ----------------
// grid (64, 16), K=2048, W2e [2048][1024]
__global__ __launch_bounds__(256) void moe2_kernel(
        const float* __restrict__ A, const float* __restrict__ w2,
        const float* __restrict__ wgt, const int* __restrict__ counts,
        const int* __restrict__ lists, float* __restrict__ out, int e) {
    const int cnt = counts[e];
    const int tile = blockIdx.x;
    if (tile*64 >= cnt) return;
    const int cbase = blockIdx.y*64;
    const float* W = w2 + (size_t)e*FFDIM*CDIM + cbase;
    __shared__ float As[16][68];
    __shared__ float Bs[16][68];
    __shared__ int   toks[64];
    __shared__ float wro[64];
    const int tid = threadIdx.x;
    if (tid < 64) {
        int rid = tile*64 + tid;
        int t = lists[e*NT + (rid < cnt ? rid : cnt-1)];
        toks[tid] = t; wro[tid] = wgt[(size_t)t*NE + e];
    }
    __syncthreads();
    const int tx = tid & 15, ty = tid >> 4;
    const int lrow = tid >> 2, lk = (tid & 3)*4;
    const int bk = tid >> 4, bn = (tid & 15)*4;
    const float* arow = A + (size_t)(tile*64 + lrow)*FFDIM;   // contiguous per-expert rows
    float acc[4][4] = {};
    for (int kc = 0; kc < FFDIM; kc += 16) {
        float4 av = *(const float4*)(arow + kc + lk);
        float4 bv = *(const float4*)(W + (size_t)(kc + bk)*CDIM + bn);
        As[lk+0][lrow] = av.x; As[lk+1][lrow] = av.y; As[lk+2][lrow] = av.z; As[lk+3][lrow] = av.w;
        *(float4*)&Bs[bk][bn] = bv;
        __syncthreads();
        #pragma unroll
        for (int kk = 0; kk < 16; kk++) {
            float4 a4 = *(const float4*)&As[kk][ty*4];
            float4 b4 = *(const float4*)&Bs[kk][tx*4];
            float a_[4] = {a4.x, a4.y, a4.z, a4.w};
            float b_[4] = {b4.x, b4.y, b4.z, b4.w};
            #pragma unroll
            for (int i = 0; i < 4; i++)
                #pragma unroll
                for (int j = 0; j < 4; j++) acc[i][j] += a_[i]*b_[j];
        }
        __syncthreads();
    }
    #pragma unroll
    for (int i = 0; i < 4; i++) {
        int row = ty*4 + i;
        if (tile*64 + row < cnt) {
            int t = toks[row]; float wv = wro[row];
            #pragma unroll
            for (int j = 0; j < 4; j++)
                atomicAdd(&out[(size_t)t*CDIM + cbase + tx*4 + j], acc[i][j]*wv);
        }
    }
}

extern "C" void kernel_launch(void* const* d_in, const int* in_sizes, int n_in,
                              void* d_out, int out_size, void* d_ws, size_t ws_size,
                              hipStream_t stream) {
    const float* x     = (const float*)d_in[0];
    const int*   pos   = (const int*)d_in[1];
    const float* asim  = (const float*)d_in[2];
    const float* agate = (const float*)d_in[3];
    const float* qw    = (const float*)d_in[4];
    const float* kw    = (const float*)d_in[5];
    const float* vw    = (const float*)d_in[6];
    const float* ow    = (const float*)d_in[7];
    const float* msim  = (const float*)d_in[8];
    const float* mgate = (const float*)d_in[9];
    const float* w1    = (const float*)d_in[10];
    const float* w2    = (const float*)d_in[11];
    const int*   kqa   = (const int*)d_in[12];
    const int*   kqm   = (const int*)d_in[13];

    char* ws = (char*)d_ws;
    int*   counts_a = (int*)(ws + OFF_COUNTS_A);
    int*   counts_m = (int*)(ws + OFF_COUNTS_M);
    float* colinv   = (float*)(ws + OFF_COLINV);
    float* w_a      = (float*)(ws + OFF_W_A);
    float* w_m      = (float*)(ws + OFF_W_M);
    int*   list_a   = (int*)(ws + OFF_LIST_A);
    int*   list_m   = (int*)(ws + OFF_LIST_M);
    float* qb = (float*)(ws + OFF_Q);
    float* kb = (float*)(ws + OFF_K);
    float* vb = (float*)(ws + OFF_V);
    float* ao = (float*)(ws + OFF_AO);
    float* hb = (float*)(ws + OFF_H);
    float* Ab = (float*)(ws + OFF_ABUF);
    float* out = (float*)d_out;

    // zero atomics targets
    (void)hipMemsetAsync(ws + OFF_COUNTS_A, 0, 128, stream);
    (void)hipMemsetAsync(ws + OFF_Q, 0, (size_t)3*NT*DDIM*4, stream);

    colnorm_kernel<<<16, 256, 0, stream>>>(asim, msim, colinv);

    // ----- attention branch -----
    gating_kernel<<<NT, 256, 0, stream>>>(x, asim, agate, colinv, kqa, w_a, counts_a, list_a);
    qkv_kernel<<<dim3(64, 6, NE), 256, 0, stream>>>(x, qw, kw, vw, w_a, counts_a, list_a, qb, kb, vb);
    rope_kernel<<<NT, 64, 0, stream>>>(qb, kb, pos);
    attn_kernel<<<dim3(TSEQ/64, NB), 256, 0, stream>>>(qb, kb, vb, ao);
    (void)hipMemcpyAsync(hb, x, (size_t)NT*CDIM*4, hipMemcpyDeviceToDevice, stream);
    oproj_kernel<<<dim3(64, 16, NE), 256, 0, stream>>>(ao, ow, w_a, counts_a, list_a, hb);

    // h done -> copy to out, MoE adds on top
    (void)hipMemcpyAsync(out, hb, (size_t)NT*CDIM*4, hipMemcpyDeviceToDevice, stream);

    // ----- MoE branch -----
    gating_kernel<<<NT, 256, 0, stream>>>(hb, msim, mgate, colinv + NE, kqm, w_m, counts_m, list_m);
    for (int e = 0; e < NE; e++) {
        moe1_kernel<<<dim3(64, 32), 256, 0, stream>>>(hb, w1, counts_m, list_m, Ab, e);
        moe2_kernel<<<dim3(64, 16), 256, 0, stream>>>(Ab, w2, w_m, counts_m, list_m, out, e);
    }
}

// Round 3
// 1371.074 us; speedup vs baseline: 3.0239x; 3.0239x over previous
//
#include <hip/hip_runtime.h>
#include <cstdint>

#define NB   2
#define TSEQ 2048
#define NT   4096
#define CDIM 1024
#define DDIM 128
#define FFDIM 2048
#define NE   8

#define MB(x) ((size_t)(x) << 20)

// ---- workspace layout ----
#define OFF_CA   ((size_t)0)
#define OFF_CM   ((size_t)64)
#define OFF_CI   ((size_t)128)
#define OFF_WA   ((size_t)1024)
#define OFF_WM   (OFF_WA + (size_t)NT*NE*4)
#define OFF_LA   (OFF_WM + (size_t)NT*NE*4)
#define OFF_LM   (OFF_LA + (size_t)NT*NE*4)
#define OFF_QB   MB(1)
#define OFF_KB   (OFF_QB + MB(2))
#define OFF_VB   (OFF_KB + MB(2))
#define OFF_AOB  (OFF_VB + MB(2))
#define OFF_HB   MB(9)
#define OFF_AB   MB(25)                      // bf16 NT*FFDIM
#define OFF_OP   MB(41)                      // 2*16*16*128*128*4 = 32MB
#define OFF_ML   (OFF_OP + (size_t)2*16*16*128*128*4)
#define OFF_XBF  MB(78)
#define OFF_HBF  MB(86)
#define OFF_AOBF MB(94)
#define OFF_WQT  MB(95)
#define OFF_WKT  MB(97)
#define OFF_WVT  MB(99)
#define OFF_WOT  MB(101)
#define OFF_W1T  MB(103)
#define OFF_W2T  MB(107)
// end ~111MB

typedef __attribute__((ext_vector_type(8))) short bf16x8;
typedef __attribute__((ext_vector_type(4))) float f32x4;

__device__ __forceinline__ float gelu_tanh(float x) {
    float x3 = x*x*x;
    return 0.5f*x*(1.0f + tanhf(0.79788456080286535588f*(x + 0.044715f*x3)));
}

__device__ __forceinline__ unsigned short f2bf(float f) {
    union { float f; uint32_t u; } v; v.f = f;
    uint32_t r = (v.u + 0x7fff + ((v.u >> 16) & 1)) >> 16;
    return (unsigned short)r;
}

// ---------------- elementwise fp32 -> bf16 ----------------
__global__ void cvt_bf16(const float* __restrict__ in, unsigned short* __restrict__ out, int n) {
    int i = (blockIdx.x*256 + threadIdx.x)*8;
    if (i >= n) return;
    float4 a = *(const float4*)(in + i);
    float4 b = *(const float4*)(in + i + 4);
    unsigned short t[8] = {f2bf(a.x), f2bf(a.y), f2bf(a.z), f2bf(a.w),
                           f2bf(b.x), f2bf(b.y), f2bf(b.z), f2bf(b.w)};
    *(uint4*)(out + i) = *(uint4*)t;
}

// ---------------- transpose + convert: fp32 [R][C] -> bf16 [C][R] ----------------
__global__ __launch_bounds__(256) void transpose_cvt(const float* __restrict__ in,
        unsigned short* __restrict__ out, int R, int C) {
    const float* inp = in + (size_t)blockIdx.z*R*C;
    unsigned short* outp = out + (size_t)blockIdx.z*R*C;
    int rb = blockIdx.y*64, cb = blockIdx.x*64;
    __shared__ unsigned short T[64][65];
    int tid = threadIdx.x;
    int lr = tid >> 2, lc0 = (tid & 3)*16;
    const float* src = inp + (size_t)(rb + lr)*C + cb + lc0;
    #pragma unroll
    for (int i = 0; i < 16; i += 4) {
        float4 f = *(const float4*)(src + i);
        T[lr][lc0+i+0] = f2bf(f.x); T[lr][lc0+i+1] = f2bf(f.y);
        T[lr][lc0+i+2] = f2bf(f.z); T[lr][lc0+i+3] = f2bf(f.w);
    }
    __syncthreads();
    int oc = tid >> 2, or0 = (tid & 3)*16;
    unsigned short tmp[16];
    #pragma unroll
    for (int i = 0; i < 16; i++) tmp[i] = T[or0+i][oc];
    *(uint4*)(outp + (size_t)(cb+oc)*R + rb + or0)     = *(uint4*)&tmp[0];
    *(uint4*)(outp + (size_t)(cb+oc)*R + rb + or0 + 8) = *(uint4*)&tmp[8];
}

// ---------------- column norms of sim matrices ----------------
__global__ void colnorm_kernel(const float* __restrict__ asim,
                               const float* __restrict__ msim,
                               float* __restrict__ inv) {
    int col = blockIdx.x;
    const float* s = (col < NE) ? asim : msim;
    int e = col & (NE-1);
    int tid = threadIdx.x;
    float ss = 0.0f;
    for (int c = tid; c < CDIM; c += 256) { float v = s[(size_t)c*NE + e]; ss += v*v; }
    __shared__ float red[256];
    red[tid] = ss; __syncthreads();
    for (int st = 128; st > 0; st >>= 1) { if (tid < st) red[tid] += red[tid+st]; __syncthreads(); }
    if (tid == 0) inv[col] = 1.0f / fmaxf(sqrtf(red[0]), 1e-12f);
}

// ---------------- gating ----------------
__global__ void gating_kernel(const float* __restrict__ xin,
                              const float* __restrict__ sim,
                              const float* __restrict__ gates,
                              const float* __restrict__ colinv,
                              const int* __restrict__ kmin_p,
                              float* __restrict__ wout,
                              int* __restrict__ counts,
                              int* __restrict__ lists) {
    const int n = blockIdx.x, tid = threadIdx.x;
    const float* xr = xin + (size_t)n*CDIM;
    float4 xv = *(const float4*)(xr + tid*4);
    float acc[9];
    acc[0] = xv.x*xv.x + xv.y*xv.y + xv.z*xv.z + xv.w*xv.w;
    int c = tid*4;
    #pragma unroll
    for (int e = 0; e < NE; e++)
        acc[1+e] = xv.x*sim[(size_t)(c+0)*NE+e] + xv.y*sim[(size_t)(c+1)*NE+e]
                 + xv.z*sim[(size_t)(c+2)*NE+e] + xv.w*sim[(size_t)(c+3)*NE+e];
    __shared__ float red[9][256];
    #pragma unroll
    for (int a = 0; a < 9; a++) red[a][tid] = acc[a];
    __syncthreads();
    for (int s = 128; s > 0; s >>= 1) {
        if (tid < s) {
            #pragma unroll
            for (int a = 0; a < 9; a++) red[a][tid] += red[a][tid+s];
        }
        __syncthreads();
    }
    if (tid == 0) {
        float xinv = 1.0f / fmaxf(sqrtf(red[0][0]), 1e-12f);
        float logits[NE], gated[NE];
        int mask[NE]; int any = 0;
        #pragma unroll
        for (int e = 0; e < NE; e++) {
            float lg = red[1+e][0]*xinv*colinv[e] - 1.0f/(1.0f + expf(-gates[e]));
            logits[e] = lg; gated[e] = fmaxf(lg, 0.0f);
            mask[e] = (lg > 0.0f) ? 1 : 0; any |= mask[e];
        }
        if (!any) {
            int kmin = *kmin_p; if (kmin < 1) kmin = 1; if (kmin > NE) kmin = NE;
            int used[NE] = {0,0,0,0,0,0,0,0};
            for (int kk = 0; kk < kmin; kk++) {
                int best = -1; float bv = 0.0f;
                for (int e = 0; e < NE; e++)
                    if (!used[e] && (best < 0 || logits[e] > bv)) { best = e; bv = logits[e]; }
                used[best] = 1; mask[best] = 1;
            }
        }
        float mx = -3.402823466e38f;
        #pragma unroll
        for (int e = 0; e < NE; e++) { float me = mask[e] ? gated[e] : -1.0e9f; mx = fmaxf(mx, me); }
        float sum = 0.0f, p[NE];
        #pragma unroll
        for (int e = 0; e < NE; e++) { p[e] = expf((mask[e] ? gated[e] : -1.0e9f) - mx); sum += p[e]; }
        float sinv = 1.0f / sum;
        #pragma unroll
        for (int e = 0; e < NE; e++) {
            float w = mask[e] ? p[e]*sinv : 0.0f;
            wout[(size_t)n*NE + e] = w;
            if (mask[e]) { int pos = atomicAdd(&counts[e], 1); lists[e*NT + pos] = n; }
        }
    }
}

// ---------------- grouped bf16 MFMA GEMM ----------------
// 128x128 tile, BK=32, 256 thr (4 waves 2x2), wave tile 64x64 = 4x4 frags of 16x16x32.
#define GM_QKV   0
#define GM_OPROJ 1
#define GM_MOE1  2
#define GM_MOE2  3

template<int MODE, int K, int N>
__global__ __launch_bounds__(256) void ggemm(
        const unsigned short* __restrict__ Abase,   // bf16 rows [*, K]
        const unsigned short* __restrict__ Bt_,     // bf16 [e][N][K] (or per-expert buf)
        const float* __restrict__ wgt_,
        const int* __restrict__ counts_,
        const int* __restrict__ lists_,
        float* __restrict__ d0, float* __restrict__ d1, float* __restrict__ d2,
        unsigned short* __restrict__ du,
        int eFix) {
    const int e = (eFix >= 0) ? eFix : blockIdx.z;
    const int cnt = counts_[e];
    const int tm = blockIdx.x;
    if (tm*128 >= cnt) return;
    int n0 = 0;
    const unsigned short* Bt = Bt_;
    float* dst = d0;
    if constexpr (MODE == GM_QKV) {
        int yy = blockIdx.y;
        Bt = Bt_ + (size_t)yy*((size_t)NE*N*K);
        dst = (yy == 0) ? d0 : (yy == 1) ? d1 : d2;
    } else {
        n0 = blockIdx.y*128;
    }
    const int eB = (MODE == GM_QKV || MODE == GM_OPROJ) ? e : 0;
    const unsigned short* Bexp = Bt + (size_t)eB*N*K + (size_t)n0*K;

    __shared__ unsigned short As[128][32];
    __shared__ unsigned short Bs[128][32];
    __shared__ int   toks[128];
    __shared__ float wro[128];
    const int tid = threadIdx.x;
    for (int i = tid; i < 128; i += 256) {
        int rid = tm*128 + i;
        int t = lists_[e*NT + (rid < cnt ? rid : cnt-1)];
        toks[i] = t;
        wro[i] = wgt_[(size_t)t*NE + e];
    }
    __syncthreads();

    const int lane = tid & 63, wid = tid >> 6;
    const int wr = wid >> 1, wc = wid & 1;
    const int fr = lane & 15, ks = lane >> 4;

    f32x4 acc[4][4];
    #pragma unroll
    for (int i = 0; i < 4; i++)
        #pragma unroll
        for (int j = 0; j < 4; j++) acc[i][j] = (f32x4){0.f, 0.f, 0.f, 0.f};

    for (int k0 = 0; k0 < K; k0 += 32) {
        #pragma unroll
        for (int s = 0; s < 2; s++) {
            int sl = tid + s*256;
            int r = sl >> 2, q = (sl & 3)*8;
            const unsigned short* asrc;
            if constexpr (MODE == GM_MOE2) {
                int pos = tm*128 + r; if (pos >= cnt) pos = cnt-1;
                asrc = Abase + (size_t)pos*K;
            } else {
                asrc = Abase + (size_t)toks[r]*K;
            }
            *(uint4*)&As[r][q] = *(const uint4*)(asrc + k0 + q);
            *(uint4*)&Bs[r][q] = *(const uint4*)(Bexp + (size_t)r*K + k0 + q);
        }
        __syncthreads();
        bf16x8 af[4], bg[4];
        #pragma unroll
        for (int m = 0; m < 4; m++) af[m] = *(const bf16x8*)&As[wr*64 + m*16 + fr][ks*8];
        #pragma unroll
        for (int n = 0; n < 4; n++) bg[n] = *(const bf16x8*)&Bs[wc*64 + n*16 + fr][ks*8];
        #pragma unroll
        for (int m = 0; m < 4; m++)
            #pragma unroll
            for (int n = 0; n < 4; n++)
                acc[m][n] = __builtin_amdgcn_mfma_f32_16x16x32_bf16(af[m], bg[n], acc[m][n], 0, 0, 0);
        __syncthreads();
    }

    #pragma unroll
    for (int m = 0; m < 4; m++) {
        #pragma unroll
        for (int rg = 0; rg < 4; rg++) {
            int lr = wr*64 + m*16 + ks*4 + rg;
            if (tm*128 + lr >= cnt) continue;
            int t = toks[lr]; float wv = wro[lr];
            #pragma unroll
            for (int n = 0; n < 4; n++) {
                int gc = n0 + wc*64 + n*16 + fr;
                float v = acc[m][n][rg];
                if constexpr (MODE == GM_QKV)
                    atomicAdd(dst + (size_t)t*DDIM + gc, v*wv);
                else if constexpr (MODE == GM_OPROJ)
                    atomicAdd(dst + (size_t)t*CDIM + gc, v*wv);
                else if constexpr (MODE == GM_MOE1)
                    du[(size_t)(tm*128 + lr)*FFDIM + gc] = f2bf(gelu_tanh(v));
                else
                    dst[(size_t)t*CDIM + gc] += v*wv;
            }
        }
    }
}

// ---------------- RoPE ----------------
__global__ void rope_kernel(float* __restrict__ q, float* __restrict__ k,
                            const int* __restrict__ pos_ids) {
    int n = blockIdx.x, j = threadIdx.x;
    float pos = (float)pos_ids[n];
    float inv = expf(-((float)j / 64.0f) * 9.21034037197618274f);
    float ang = pos * inv;
    float c = cosf(ang), s = sinf(ang);
    float* qr = q + (size_t)n*DDIM;
    float* kr = k + (size_t)n*DDIM;
    float q0 = qr[j], q1 = qr[j+64];
    qr[j]    = q0*c - q1*s;
    qr[j+64] = q1*c + q0*s;
    float k0 = kr[j], k1 = kr[j+64];
    kr[j]    = k0*c - k1*s;
    kr[j+64] = k1*c + k0*s;
}

// ---------------- split-KV flash attention partials ----------------
// grid (16 q-blocks of 128 rows, 16 kv-chunks of 128, B). 256 thr.
// thread (r=tid>>2, qq=tid&3) owns rows r and r+64, dims {qq+4m}.
__global__ __launch_bounds__(256) void attn_part(const float* __restrict__ q,
        const float* __restrict__ kbuf, const float* __restrict__ vbuf,
        float* __restrict__ Opart, float* __restrict__ ml) {
    const int qt = blockIdx.x, ch = blockIdx.y, b = blockIdx.z;
    if (ch > qt) return;
    const int tid = threadIdx.x;
    const int r = tid >> 2, qq = tid & 3;
    const int row0 = qt*128 + r;
    const float scale = 0.08838834764831845f;
    __shared__ float Ks[32][132];
    __shared__ float Vs[32][132];
    float q0[32], q1[32];
    {
        const float* p0 = q + ((size_t)b*TSEQ + row0)*DDIM + qq;
        const float* p1 = p0 + 64*DDIM;
        #pragma unroll
        for (int m = 0; m < 32; m++) { q0[m] = p0[4*m]*scale; q1[m] = p1[4*m]*scale; }
    }
    float O0[32] = {}, O1[32] = {};
    float m0 = -INFINITY, l0 = 0.f, m1 = -INFINITY, l1 = 0.f;
    const bool diag = (ch == qt);
    for (int kt = 0; kt < 4; kt++) {
        const int kvbase = ch*128 + kt*32;
        for (int i = tid; i < 1024; i += 256) {
            int row = i >> 5, c4 = (i & 31)*4;
            *(float4*)&Ks[row][c4] = *(const float4*)&kbuf[((size_t)b*TSEQ + kvbase + row)*DDIM + c4];
            *(float4*)&Vs[row][c4] = *(const float4*)&vbuf[((size_t)b*TSEQ + kvbase + row)*DDIM + c4];
        }
        __syncthreads();
        #pragma unroll
        for (int half = 0; half < 2; half++) {
            float s0[16], s1[16];
            #pragma unroll
            for (int cc = 0; cc < 16; cc++) {
                int c = half*16 + cc;
                float a0 = 0.f, a1 = 0.f;
                #pragma unroll
                for (int m = 0; m < 32; m++) {
                    float kv = Ks[c][qq + 4*m];
                    a0 += q0[m]*kv; a1 += q1[m]*kv;
                }
                s0[cc] = a0; s1[cc] = a1;
            }
            #pragma unroll
            for (int cc = 0; cc < 16; cc++) {
                s0[cc] += __shfl_xor(s0[cc], 1); s0[cc] += __shfl_xor(s0[cc], 2);
                s1[cc] += __shfl_xor(s1[cc], 1); s1[cc] += __shfl_xor(s1[cc], 2);
            }
            float a_ml0 = -INFINITY, a_ml1 = -INFINITY;
            #pragma unroll
            for (int cc = 0; cc < 16; cc++) {
                int kvi = kvbase + half*16 + cc;
                if (diag) {
                    if (kvi > row0) s0[cc] = -3.402823466e38f;
                    if (kvi > row0 + 64) s1[cc] = -3.402823466e38f;
                }
                a_ml0 = fmaxf(a_ml0, s0[cc]); a_ml1 = fmaxf(a_ml1, s1[cc]);
            }
            float mn0 = fmaxf(fmaxf(m0, a_ml0), -1e30f);
            float mn1 = fmaxf(fmaxf(m1, a_ml1), -1e30f);
            float al0 = expf(m0 - mn0), al1 = expf(m1 - mn1);
            float ls0 = 0.f, ls1 = 0.f;
            #pragma unroll
            for (int cc = 0; cc < 16; cc++) {
                s0[cc] = expf(s0[cc] - mn0); ls0 += s0[cc];
                s1[cc] = expf(s1[cc] - mn1); ls1 += s1[cc];
            }
            l0 = l0*al0 + ls0; l1 = l1*al1 + ls1;
            m0 = mn0; m1 = mn1;
            #pragma unroll
            for (int m = 0; m < 32; m++) { O0[m] *= al0; O1[m] *= al1; }
            #pragma unroll
            for (int cc = 0; cc < 16; cc++) {
                float p0v = s0[cc], p1v = s1[cc];
                #pragma unroll
                for (int m = 0; m < 32; m++) {
                    float vv = Vs[half*16 + cc][qq + 4*m];
                    O0[m] += p0v*vv; O1[m] += p1v*vv;
                }
            }
        }
        __syncthreads();
    }
    const size_t idx = (((size_t)b*16 + qt)*16 + ch);
    float* op = Opart + idx*(128*128);
    #pragma unroll
    for (int m = 0; m < 32; m++) {
        op[(size_t)r*128 + qq + 4*m]       = O0[m];
        op[(size_t)(r+64)*128 + qq + 4*m]  = O1[m];
    }
    if (qq == 0) {
        float* mlp = ml + idx*256;
        mlp[r*2] = m0;        mlp[r*2 + 1] = l0;
        mlp[(r+64)*2] = m1;   mlp[(r+64)*2 + 1] = l1;
    }
}

// grid (16, B), 512 thr: r = tid>>2 in 0..127
__global__ __launch_bounds__(512) void attn_reduce(const float* __restrict__ Opart,
        const float* __restrict__ ml, float* __restrict__ ao) {
    const int qt = blockIdx.x, b = blockIdx.y;
    const int tid = threadIdx.x;
    const int r = tid >> 2, qq = tid & 3;
    const int nch = qt + 1;
    const size_t base = ((size_t)b*16 + qt)*16;
    float M = -INFINITY;
    for (int i = 0; i < nch; i++) M = fmaxf(M, ml[(base+i)*256 + r*2]);
    float L = 0.f;
    for (int i = 0; i < nch; i++) {
        float mi = ml[(base+i)*256 + r*2], li = ml[(base+i)*256 + r*2 + 1];
        L += li*expf(mi - M);
    }
    float o[32] = {};
    for (int i = 0; i < nch; i++) {
        float sc = expf(ml[(base+i)*256 + r*2] - M);
        const float* op = Opart + (base+i)*(128*128) + (size_t)r*128 + qq;
        #pragma unroll
        for (int m = 0; m < 32; m++) o[m] += sc*op[4*m];
    }
    float linv = 1.0f / L;
    float* dst = ao + ((size_t)b*TSEQ + qt*128 + r)*DDIM + qq;
    #pragma unroll
    for (int m = 0; m < 32; m++) dst[4*m] = o[m]*linv;
}

extern "C" void kernel_launch(void* const* d_in, const int* in_sizes, int n_in,
                              void* d_out, int out_size, void* d_ws, size_t ws_size,
                              hipStream_t stream) {
    const float* x     = (const float*)d_in[0];
    const int*   pos   = (const int*)d_in[1];
    const float* asim  = (const float*)d_in[2];
    const float* agate = (const float*)d_in[3];
    const float* qw    = (const float*)d_in[4];
    const float* kw    = (const float*)d_in[5];
    const float* vw    = (const float*)d_in[6];
    const float* ow    = (const float*)d_in[7];
    const float* msim  = (const float*)d_in[8];
    const float* mgate = (const float*)d_in[9];
    const float* w1    = (const float*)d_in[10];
    const float* w2    = (const float*)d_in[11];
    const int*   kqa   = (const int*)d_in[12];
    const int*   kqm   = (const int*)d_in[13];

    char* ws = (char*)d_ws;
    int*   counts_a = (int*)(ws + OFF_CA);
    int*   counts_m = (int*)(ws + OFF_CM);
    float* colinv   = (float*)(ws + OFF_CI);
    float* w_a      = (float*)(ws + OFF_WA);
    float* w_m      = (float*)(ws + OFF_WM);
    int*   list_a   = (int*)(ws + OFF_LA);
    int*   list_m   = (int*)(ws + OFF_LM);
    float* qb   = (float*)(ws + OFF_QB);
    float* kb   = (float*)(ws + OFF_KB);
    float* vb   = (float*)(ws + OFF_VB);
    float* ao   = (float*)(ws + OFF_AOB);
    float* hb   = (float*)(ws + OFF_HB);
    unsigned short* Ab   = (unsigned short*)(ws + OFF_AB);
    float* Opart = (float*)(ws + OFF_OP);
    float* mlb   = (float*)(ws + OFF_ML);
    unsigned short* xbf  = (unsigned short*)(ws + OFF_XBF);
    unsigned short* hbf  = (unsigned short*)(ws + OFF_HBF);
    unsigned short* aobf = (unsigned short*)(ws + OFF_AOBF);
    unsigned short* wqt  = (unsigned short*)(ws + OFF_WQT);
    unsigned short* wot  = (unsigned short*)(ws + OFF_WOT);
    unsigned short* w1t  = (unsigned short*)(ws + OFF_W1T);
    unsigned short* w2t  = (unsigned short*)(ws + OFF_W2T);
    float* out = (float*)d_out;

    (void)hipMemsetAsync(ws + OFF_CA, 0, 128, stream);
    (void)hipMemsetAsync(ws + OFF_QB, 0, MB(6), stream);     // q,k,v

    colnorm_kernel<<<16, 256, 0, stream>>>(asim, msim, colinv);
    cvt_bf16<<<NT*CDIM/2048, 256, 0, stream>>>(x, xbf, NT*CDIM);

    // weight transposes: [e][K][N] -> [e][N][K] bf16
    transpose_cvt<<<dim3(2, 16, NE), 256, 0, stream>>>(qw, wqt, CDIM, DDIM);
    transpose_cvt<<<dim3(2, 16, NE), 256, 0, stream>>>(kw, (unsigned short*)(ws + OFF_WKT), CDIM, DDIM);
    transpose_cvt<<<dim3(2, 16, NE), 256, 0, stream>>>(vw, (unsigned short*)(ws + OFF_WVT), CDIM, DDIM);
    transpose_cvt<<<dim3(16, 2, NE), 256, 0, stream>>>(ow, wot, DDIM, CDIM);

    // ----- attention branch -----
    gating_kernel<<<NT, 256, 0, stream>>>(x, asim, agate, colinv, kqa, w_a, counts_a, list_a);
    ggemm<GM_QKV, CDIM, DDIM><<<dim3(NT/128, 3, NE), 256, 0, stream>>>(
        xbf, wqt, w_a, counts_a, list_a, qb, kb, vb, nullptr, -1);
    rope_kernel<<<NT, 64, 0, stream>>>(qb, kb, pos);
    attn_part<<<dim3(16, 16, NB), 256, 0, stream>>>(qb, kb, vb, Opart, mlb);
    attn_reduce<<<dim3(16, NB), 512, 0, stream>>>(Opart, mlb, ao);
    cvt_bf16<<<NT*DDIM/2048, 256, 0, stream>>>(ao, aobf, NT*DDIM);

    (void)hipMemcpyAsync(hb, x, (size_t)NT*CDIM*4, hipMemcpyDeviceToDevice, stream);
    ggemm<GM_OPROJ, DDIM, CDIM><<<dim3(NT/128, 8, NE), 256, 0, stream>>>(
        aobf, wot, w_a, counts_a, list_a, hb, nullptr, nullptr, nullptr, -1);

    (void)hipMemcpyAsync(out, hb, (size_t)NT*CDIM*4, hipMemcpyDeviceToDevice, stream);
    cvt_bf16<<<NT*CDIM/2048, 256, 0, stream>>>(hb, hbf, NT*CDIM);

    // ----- MoE branch -----
    gating_kernel<<<NT, 256, 0, stream>>>(hb, msim, mgate, colinv + NE, kqm, w_m, counts_m, list_m);
    for (int e = 0; e < NE; e++) {
        transpose_cvt<<<dim3(32, 16, 1), 256, 0, stream>>>(w1 + (size_t)e*CDIM*FFDIM, w1t, CDIM, FFDIM);
        transpose_cvt<<<dim3(16, 32, 1), 256, 0, stream>>>(w2 + (size_t)e*FFDIM*CDIM, w2t, FFDIM, CDIM);
        ggemm<GM_MOE1, CDIM, FFDIM><<<dim3(NT/128, 16, 1), 256, 0, stream>>>(
            hbf, w1t, w_m, counts_m, list_m, nullptr, nullptr, nullptr, Ab, e);
        ggemm<GM_MOE2, FFDIM, CDIM><<<dim3(NT/128, 8, 1), 256, 0, stream>>>(
            Ab, w2t, w_m, counts_m, list_m, out, nullptr, nullptr, nullptr, e);
    }
}

// Round 5
// 846.105 us; speedup vs baseline: 4.9001x; 1.6205x over previous
//
#include <hip/hip_runtime.h>
#include <cstdint>

#define NB   2
#define TSEQ 2048
#define NT   4096
#define CDIM 1024
#define DDIM 128
#define FFDIM 2048
#define NE   8
#define ABCAP 8192

#define MB(x) ((size_t)(x) << 20)

// ---- workspace layout (121 MB total) ----
#define OFF_CA   ((size_t)0)
#define OFF_CM   ((size_t)64)
#define OFF_CI   ((size_t)128)
#define OFF_OFFS ((size_t)192)
#define OFF_WA   ((size_t)1024)
#define OFF_WM   (OFF_WA + (size_t)NT*NE*4)
#define OFF_LA   (OFF_WM + (size_t)NT*NE*4)
#define OFF_LM   (OFF_LA + (size_t)NT*NE*4)
#define OFF_QB   MB(1)
#define OFF_KB   MB(3)
#define OFF_VB   MB(5)
#define OFF_AO   MB(7)
#define OFF_QHI  MB(9)
#define OFF_QLO  MB(10)
#define OFF_KHI  MB(11)
#define OFF_KLO  MB(12)
#define OFF_VTH  MB(13)
#define OFF_VTL  MB(14)
#define OFF_AOBF MB(15)
#define OFF_ML   MB(16)
#define OFF_WQT  MB(17)
#define OFF_WKT  MB(19)
#define OFF_WVT  MB(21)
#define OFF_WOT  MB(23)
#define OFF_XBF  MB(25)
#define OFF_HBF  MB(33)
#define OFF_HB   MB(41)
#define OFF_AB   MB(57)
#define OFF_OP   MB(89)   // Opart (32MB) -> then w1t -> then w2t (sequential reuse)
#define OFF_WXT  MB(89)

typedef __attribute__((ext_vector_type(8))) short bf16x8;
typedef __attribute__((ext_vector_type(4))) float f32x4;

__device__ __forceinline__ float gelu_tanh(float x) {
    float x3 = x*x*x;
    return 0.5f*x*(1.0f + tanhf(0.79788456080286535588f*(x + 0.044715f*x3)));
}

__device__ __forceinline__ unsigned short f2bf(float f) {
    union { float f; uint32_t u; } v; v.f = f;
    uint32_t r = (v.u + 0x7fff + ((v.u >> 16) & 1)) >> 16;
    return (unsigned short)r;
}
__device__ __forceinline__ float bf2f(unsigned short h) {
    union { uint32_t u; float f; } v; v.u = ((uint32_t)h) << 16; return v.f;
}

// ---------------- fp32 -> bf16 ----------------
__global__ void cvt_bf16(const float* __restrict__ in, unsigned short* __restrict__ out, int n) {
    int i = (blockIdx.x*256 + threadIdx.x)*8;
    if (i >= n) return;
    float4 a = *(const float4*)(in + i);
    float4 b = *(const float4*)(in + i + 4);
    unsigned short t[8] = {f2bf(a.x), f2bf(a.y), f2bf(a.z), f2bf(a.w),
                           f2bf(b.x), f2bf(b.y), f2bf(b.z), f2bf(b.w)};
    *(uint4*)(out + i) = *(uint4*)t;
}

// ---------------- fused: out=h (fp32) + hbf (bf16) ----------------
__global__ void fuse_h(const float* __restrict__ hb, float* __restrict__ out,
                       unsigned short* __restrict__ hbf) {
    int i = (blockIdx.x*256 + threadIdx.x)*4;
    float4 v = *(const float4*)(hb + i);
    *(float4*)(out + i) = v;
    unsigned short t[4] = {f2bf(v.x), f2bf(v.y), f2bf(v.z), f2bf(v.w)};
    *(uint2*)(hbf + i) = *(uint2*)t;
}

// ---------------- transpose + convert: fp32 [R][C] -> bf16 [C][R] ----------------
__global__ __launch_bounds__(256) void transpose_cvt(const float* __restrict__ in,
        unsigned short* __restrict__ out, int R, int C) {
    const float* inp = in + (size_t)blockIdx.z*R*C;
    unsigned short* outp = out + (size_t)blockIdx.z*R*C;
    int rb = blockIdx.y*64, cb = blockIdx.x*64;
    __shared__ unsigned short T[64][65];
    int tid = threadIdx.x;
    int lr = tid >> 2, lc0 = (tid & 3)*16;
    const float* src = inp + (size_t)(rb + lr)*C + cb + lc0;
    #pragma unroll
    for (int i = 0; i < 16; i += 4) {
        float4 f = *(const float4*)(src + i);
        T[lr][lc0+i+0] = f2bf(f.x); T[lr][lc0+i+1] = f2bf(f.y);
        T[lr][lc0+i+2] = f2bf(f.z); T[lr][lc0+i+3] = f2bf(f.w);
    }
    __syncthreads();
    int oc = tid >> 2, or0 = (tid & 3)*16;
    unsigned short tmp[16];
    #pragma unroll
    for (int i = 0; i < 16; i++) tmp[i] = T[or0+i][oc];
    *(uint4*)(outp + (size_t)(cb+oc)*R + rb + or0)     = *(uint4*)&tmp[0];
    *(uint4*)(outp + (size_t)(cb+oc)*R + rb + or0 + 8) = *(uint4*)&tmp[8];
}

// ---------------- transpose + hi/lo split convert ----------------
__global__ __launch_bounds__(256) void transpose_cvt2(const float* __restrict__ in,
        unsigned short* __restrict__ outh, unsigned short* __restrict__ outl, int R, int C) {
    const float* inp = in + (size_t)blockIdx.z*R*C;
    unsigned short* oph = outh + (size_t)blockIdx.z*R*C;
    unsigned short* opl = outl + (size_t)blockIdx.z*R*C;
    int rb = blockIdx.y*64, cb = blockIdx.x*64;
    __shared__ unsigned short Th[64][65];
    __shared__ unsigned short Tl[64][65];
    int tid = threadIdx.x;
    int lr = tid >> 2, lc0 = (tid & 3)*16;
    const float* src = inp + (size_t)(rb + lr)*C + cb + lc0;
    #pragma unroll
    for (int i = 0; i < 16; i += 4) {
        float4 f = *(const float4*)(src + i);
        float fa[4] = {f.x, f.y, f.z, f.w};
        #pragma unroll
        for (int jj = 0; jj < 4; jj++) {
            unsigned short h = f2bf(fa[jj]);
            Th[lr][lc0+i+jj] = h;
            Tl[lr][lc0+i+jj] = f2bf(fa[jj] - bf2f(h));
        }
    }
    __syncthreads();
    int oc = tid >> 2, or0 = (tid & 3)*16;
    unsigned short th[16], tl[16];
    #pragma unroll
    for (int i = 0; i < 16; i++) { th[i] = Th[or0+i][oc]; tl[i] = Tl[or0+i][oc]; }
    size_t o = (size_t)(cb+oc)*R + rb + or0;
    *(uint4*)(oph + o)     = *(uint4*)&th[0];
    *(uint4*)(oph + o + 8) = *(uint4*)&th[8];
    *(uint4*)(opl + o)     = *(uint4*)&tl[0];
    *(uint4*)(opl + o + 8) = *(uint4*)&tl[8];
}

// ---------------- column norms ----------------
__global__ void colnorm_kernel(const float* __restrict__ asim,
                               const float* __restrict__ msim,
                               float* __restrict__ inv) {
    int col = blockIdx.x;
    const float* s = (col < NE) ? asim : msim;
    int e = col & (NE-1);
    int tid = threadIdx.x;
    float ss = 0.0f;
    for (int c = tid; c < CDIM; c += 256) { float v = s[(size_t)c*NE + e]; ss += v*v; }
    __shared__ float red[256];
    red[tid] = ss; __syncthreads();
    for (int st = 128; st > 0; st >>= 1) { if (tid < st) red[tid] += red[tid+st]; __syncthreads(); }
    if (tid == 0) inv[col] = 1.0f / fmaxf(sqrtf(red[0]), 1e-12f);
}

// ---------------- gating (round-3 proven tree-reduction version) ----------------
__global__ void gating_kernel(const float* __restrict__ xin,
                              const float* __restrict__ sim,
                              const float* __restrict__ gates,
                              const float* __restrict__ colinv,
                              const int* __restrict__ kmin_p,
                              float* __restrict__ wout,
                              int* __restrict__ counts,
                              int* __restrict__ lists) {
    const int n = blockIdx.x, tid = threadIdx.x;
    const float* xr = xin + (size_t)n*CDIM;
    float4 xv = *(const float4*)(xr + tid*4);
    float acc[9];
    acc[0] = xv.x*xv.x + xv.y*xv.y + xv.z*xv.z + xv.w*xv.w;
    int c = tid*4;
    #pragma unroll
    for (int e = 0; e < NE; e++)
        acc[1+e] = xv.x*sim[(size_t)(c+0)*NE+e] + xv.y*sim[(size_t)(c+1)*NE+e]
                 + xv.z*sim[(size_t)(c+2)*NE+e] + xv.w*sim[(size_t)(c+3)*NE+e];
    __shared__ float red[9][256];
    #pragma unroll
    for (int a = 0; a < 9; a++) red[a][tid] = acc[a];
    __syncthreads();
    for (int s = 128; s > 0; s >>= 1) {
        if (tid < s) {
            #pragma unroll
            for (int a = 0; a < 9; a++) red[a][tid] += red[a][tid+s];
        }
        __syncthreads();
    }
    if (tid == 0) {
        float xinv = 1.0f / fmaxf(sqrtf(red[0][0]), 1e-12f);
        float logits[NE], gated[NE];
        int mask[NE]; int any = 0;
        #pragma unroll
        for (int e = 0; e < NE; e++) {
            float lg = red[1+e][0]*xinv*colinv[e] - 1.0f/(1.0f + expf(-gates[e]));
            logits[e] = lg; gated[e] = fmaxf(lg, 0.0f);
            mask[e] = (lg > 0.0f) ? 1 : 0; any |= mask[e];
        }
        if (!any) {
            int kmin = *kmin_p; if (kmin < 1) kmin = 1; if (kmin > NE) kmin = NE;
            int used[NE] = {0,0,0,0,0,0,0,0};
            for (int kk = 0; kk < kmin; kk++) {
                int best = -1; float bv = 0.0f;
                for (int e = 0; e < NE; e++)
                    if (!used[e] && (best < 0 || logits[e] > bv)) { best = e; bv = logits[e]; }
                used[best] = 1; mask[best] = 1;
            }
        }
        float mx = -3.402823466e38f;
        #pragma unroll
        for (int e = 0; e < NE; e++) { float me = mask[e] ? gated[e] : -1.0e9f; mx = fmaxf(mx, me); }
        float sum = 0.0f, p[NE];
        #pragma unroll
        for (int e = 0; e < NE; e++) { p[e] = expf((mask[e] ? gated[e] : -1.0e9f) - mx); sum += p[e]; }
        float sinv = 1.0f / sum;
        #pragma unroll
        for (int e = 0; e < NE; e++) {
            float w = mask[e] ? p[e]*sinv : 0.0f;
            wout[(size_t)n*NE + e] = w;
            if (mask[e]) { int pos = atomicAdd(&counts[e], 1); lists[e*NT + pos] = n; }
        }
    }
}

__global__ void scan_counts(const int* __restrict__ counts, int* __restrict__ offs) {
    if (threadIdx.x == 0) {
        int s = 0;
        for (int e = 0; e < NE; e++) { offs[e] = s; s += counts[e]; }
    }
}

// ---------------- grouped bf16 MFMA GEMM ----------------
#define GM_QKV   0
#define GM_OPROJ 1
#define GM_MOE1  2
#define GM_MOE2  3

template<int MODE, int K, int N>
__global__ __launch_bounds__(256) void ggemm(
        const unsigned short* __restrict__ Abase,
        const unsigned short* __restrict__ Bt_,     // bf16 [e][N][K]
        const float* __restrict__ wgt_,
        const int* __restrict__ counts_,
        const int* __restrict__ lists_,
        const int* __restrict__ offs_,
        float* __restrict__ d0, float* __restrict__ d1, float* __restrict__ d2,
        unsigned short* __restrict__ du) {
    const int e = blockIdx.z;
    const int cnt = counts_[e];
    const int tm = blockIdx.x;
    if (tm*128 >= cnt) return;
    int n0 = 0;
    const unsigned short* Bt = Bt_;
    float* dst = d0;
    if constexpr (MODE == GM_QKV) {
        int yy = blockIdx.y;
        Bt = Bt_ + (size_t)yy*((size_t)NE*N*K);
        dst = (yy == 0) ? d0 : (yy == 1) ? d1 : d2;
    } else {
        n0 = blockIdx.y*128;
    }
    const int eoff = (MODE == GM_MOE1 || MODE == GM_MOE2) ? offs_[e] : 0;
    const unsigned short* Bexp = Bt + (size_t)e*N*K + (size_t)n0*K;

    __shared__ unsigned short As[128][40];
    __shared__ unsigned short Bs[128][40];
    __shared__ int   toks[128];
    __shared__ float wro[128];
    const int tid = threadIdx.x;
    for (int i = tid; i < 128; i += 256) {
        int rid = tm*128 + i;
        int t = lists_[e*NT + (rid < cnt ? rid : cnt-1)];
        toks[i] = t;
        wro[i] = wgt_[(size_t)t*NE + e];
    }
    __syncthreads();

    const int lane = tid & 63, wid = tid >> 6;
    const int wr = wid >> 1, wc = wid & 1;
    const int fr = lane & 15, ks = lane >> 4;

    f32x4 acc[4][4];
    #pragma unroll
    for (int i = 0; i < 4; i++)
        #pragma unroll
        for (int j = 0; j < 4; j++) acc[i][j] = (f32x4){0.f, 0.f, 0.f, 0.f};

    for (int k0 = 0; k0 < K; k0 += 32) {
        #pragma unroll
        for (int s = 0; s < 2; s++) {
            int sl = tid + s*256;
            int r = sl >> 2, q = (sl & 3)*8;
            const unsigned short* asrc;
            if constexpr (MODE == GM_MOE2) {
                int pos = tm*128 + r; if (pos >= cnt) pos = cnt-1;
                int row = eoff + pos; if (row > ABCAP-1) row = ABCAP-1;
                asrc = Abase + (size_t)row*K;
            } else {
                asrc = Abase + (size_t)toks[r]*K;
            }
            *(uint4*)&As[r][q] = *(const uint4*)(asrc + k0 + q);
            *(uint4*)&Bs[r][q] = *(const uint4*)(Bexp + (size_t)r*K + k0 + q);
        }
        __syncthreads();
        bf16x8 af[4], bg[4];
        #pragma unroll
        for (int m = 0; m < 4; m++) af[m] = *(const bf16x8*)&As[wr*64 + m*16 + fr][ks*8];
        #pragma unroll
        for (int n = 0; n < 4; n++) bg[n] = *(const bf16x8*)&Bs[wc*64 + n*16 + fr][ks*8];
        #pragma unroll
        for (int m = 0; m < 4; m++)
            #pragma unroll
            for (int n = 0; n < 4; n++)
                acc[m][n] = __builtin_amdgcn_mfma_f32_16x16x32_bf16(af[m], bg[n], acc[m][n], 0, 0, 0);
        __syncthreads();
    }

    #pragma unroll
    for (int m = 0; m < 4; m++) {
        #pragma unroll
        for (int rg = 0; rg < 4; rg++) {
            int lr = wr*64 + m*16 + ks*4 + rg;
            if (tm*128 + lr >= cnt) continue;
            int t = toks[lr]; float wv = wro[lr];
            #pragma unroll
            for (int n = 0; n < 4; n++) {
                int gc = n0 + wc*64 + n*16 + fr;
                float v = acc[m][n][rg];
                if constexpr (MODE == GM_QKV)
                    atomicAdd(dst + (size_t)t*DDIM + gc, v*wv);
                else if constexpr (MODE == GM_OPROJ)
                    atomicAdd(dst + (size_t)t*CDIM + gc, v*wv);
                else if constexpr (MODE == GM_MOE1) {
                    int row = eoff + tm*128 + lr;
                    if (row < ABCAP)
                        du[(size_t)row*FFDIM + gc] = f2bf(gelu_tanh(v));
                } else
                    atomicAdd(dst + (size_t)t*CDIM + gc, v*wv);
            }
        }
    }
}

// ---------------- RoPE + hi/lo bf16 split ----------------
__global__ void rope_cvt2(const float* __restrict__ q, const float* __restrict__ k,
        const int* __restrict__ pos_ids,
        unsigned short* __restrict__ qh, unsigned short* __restrict__ ql,
        unsigned short* __restrict__ kh, unsigned short* __restrict__ kl) {
    int n = blockIdx.x, j = threadIdx.x;   // j in 0..63
    float pos = (float)pos_ids[n];
    float inv = expf(-((float)j / 64.0f) * 9.21034037197618274f);
    float ang = pos * inv;
    float c = cosf(ang), s = sinf(ang);
    const float* qr = q + (size_t)n*DDIM;
    const float* kr = k + (size_t)n*DDIM;
    size_t base = (size_t)n*DDIM;
    float v0 = qr[j], v1 = qr[j+64];
    float a = v0*c - v1*s, b2 = v1*c + v0*s;
    unsigned short h;
    h = f2bf(a);  qh[base+j]    = h; ql[base+j]    = f2bf(a  - bf2f(h));
    h = f2bf(b2); qh[base+j+64] = h; ql[base+j+64] = f2bf(b2 - bf2f(h));
    v0 = kr[j]; v1 = kr[j+64];
    a = v0*c - v1*s; b2 = v1*c + v0*s;
    h = f2bf(a);  kh[base+j]    = h; kl[base+j]    = f2bf(a  - bf2f(h));
    h = f2bf(b2); kh[base+j+64] = h; kl[base+j+64] = f2bf(b2 - bf2f(h));
}

// ---------------- split-precision MFMA split-KV flash attention ----------------
// grid (qt=32, ch=16, b=2), 256 thr = 4 waves; wave owns 16 q rows; chunk = 128 kv.
// Effective-fp32: S = Kh*Qh + Kh*Ql + Kl*Qh ; O = Vh*Ph + Vh*Pl + Vl*Ph.
__global__ __launch_bounds__(256) void attn_part(
        const unsigned short* __restrict__ qh_, const unsigned short* __restrict__ ql_,
        const unsigned short* __restrict__ kh_, const unsigned short* __restrict__ kl_,
        const unsigned short* __restrict__ vTh, const unsigned short* __restrict__ vTl,
        float* __restrict__ Opart, float* __restrict__ ml) {
    const int qt = blockIdx.x, ch = blockIdx.y, b = blockIdx.z;
    const int qmax = qt*64 + 63;
    if (ch*128 > qmax) return;
    const int tid = threadIdx.x;
    const int w = tid >> 6, lane = tid & 63;
    const int c = lane & 15, g = lane >> 4;
    const int qrow = qt*64 + w*16 + c;
    const float scale = 0.08838834764831845f;

    __shared__ unsigned short Ph[4][16][72];
    __shared__ unsigned short Pl[4][16][72];

    bf16x8 qfh[4], qfl[4];
    const size_t qoff = ((size_t)b*TSEQ + qrow)*DDIM;
    #pragma unroll
    for (int ds = 0; ds < 4; ds++) {
        qfh[ds] = *(const bf16x8*)(qh_ + qoff + ds*32 + g*8);
        qfl[ds] = *(const bf16x8*)(ql_ + qoff + ds*32 + g*8);
    }

    f32x4 Oa[8];
    #pragma unroll
    for (int i = 0; i < 8; i++) Oa[i] = (f32x4){0.f, 0.f, 0.f, 0.f};
    float mrun = -INFINITY, lrun = 0.f;

    for (int t = 0; t < 2; t++) {
        const int kv0 = ch*128 + t*64;
        if (kv0 > qmax) break;
        f32x4 Sa[4];
        #pragma unroll
        for (int m = 0; m < 4; m++) Sa[m] = (f32x4){0.f, 0.f, 0.f, 0.f};
        #pragma unroll
        for (int ds = 0; ds < 4; ds++) {
            #pragma unroll
            for (int m = 0; m < 4; m++) {
                const size_t ko = ((size_t)b*TSEQ + kv0 + m*16 + c)*DDIM + ds*32 + g*8;
                bf16x8 kfh = *(const bf16x8*)(kh_ + ko);
                bf16x8 kfl = *(const bf16x8*)(kl_ + ko);
                Sa[m] = __builtin_amdgcn_mfma_f32_16x16x32_bf16(kfh, qfh[ds], Sa[m], 0, 0, 0);
                Sa[m] = __builtin_amdgcn_mfma_f32_16x16x32_bf16(kfh, qfl[ds], Sa[m], 0, 0, 0);
                Sa[m] = __builtin_amdgcn_mfma_f32_16x16x32_bf16(kfl, qfh[ds], Sa[m], 0, 0, 0);
            }
        }
        float sv[16]; float mloc = -INFINITY;
        #pragma unroll
        for (int m = 0; m < 4; m++)
            #pragma unroll
            for (int r = 0; r < 4; r++) {
                int kv = kv0 + m*16 + g*4 + r;
                float s = Sa[m][r]*scale;
                if (kv > qrow) s = -3.0e38f;
                sv[m*4+r] = s;
                mloc = fmaxf(mloc, s);
            }
        mloc = fmaxf(mloc, __shfl_xor(mloc, 16));
        mloc = fmaxf(mloc, __shfl_xor(mloc, 32));
        float mnew = fmaxf(fmaxf(mrun, mloc), -1.0e30f);
        float alpha = expf(mrun - mnew);
        float ls = 0.f;
        #pragma unroll
        for (int i = 0; i < 16; i++) { sv[i] = expf(sv[i] - mnew); ls += sv[i]; }
        ls += __shfl_xor(ls, 16); ls += __shfl_xor(ls, 32);
        lrun = lrun*alpha + ls; mrun = mnew;
        #pragma unroll
        for (int i = 0; i < 8; i++) Oa[i] *= alpha;
        // P hi/lo -> LDS
        #pragma unroll
        for (int m = 0; m < 4; m++) {
            unsigned short h0 = f2bf(sv[m*4+0]), h1 = f2bf(sv[m*4+1]);
            unsigned short h2 = f2bf(sv[m*4+2]), h3 = f2bf(sv[m*4+3]);
            unsigned int* ph = (unsigned int*)&Ph[w][c][m*16 + g*4];
            ph[0] = (unsigned int)h0 | ((unsigned int)h1 << 16);
            ph[1] = (unsigned int)h2 | ((unsigned int)h3 << 16);
            unsigned short l0 = f2bf(sv[m*4+0] - bf2f(h0)), l1 = f2bf(sv[m*4+1] - bf2f(h1));
            unsigned short l2 = f2bf(sv[m*4+2] - bf2f(h2)), l3 = f2bf(sv[m*4+3] - bf2f(h3));
            unsigned int* pl = (unsigned int*)&Pl[w][c][m*16 + g*4];
            pl[0] = (unsigned int)l0 | ((unsigned int)l1 << 16);
            pl[1] = (unsigned int)l2 | ((unsigned int)l3 << 16);
        }
        #pragma unroll
        for (int ksx = 0; ksx < 2; ksx++) {
            bf16x8 pfh = *(const bf16x8*)&Ph[w][c][ksx*32 + g*8];
            bf16x8 pfl = *(const bf16x8*)&Pl[w][c][ksx*32 + g*8];
            #pragma unroll
            for (int dt = 0; dt < 8; dt++) {
                const size_t vo = ((size_t)b*DDIM + c + dt*16)*TSEQ + kv0 + ksx*32 + g*8;
                bf16x8 vfh = *(const bf16x8*)(vTh + vo);
                bf16x8 vfl = *(const bf16x8*)(vTl + vo);
                Oa[dt] = __builtin_amdgcn_mfma_f32_16x16x32_bf16(vfh, pfh, Oa[dt], 0, 0, 0);
                Oa[dt] = __builtin_amdgcn_mfma_f32_16x16x32_bf16(vfh, pfl, Oa[dt], 0, 0, 0);
                Oa[dt] = __builtin_amdgcn_mfma_f32_16x16x32_bf16(vfl, pfh, Oa[dt], 0, 0, 0);
            }
        }
    }
    const size_t base = (((size_t)b*32 + qt)*16 + ch)*64;
    float* op = Opart + (base + w*16 + c)*DDIM;
    #pragma unroll
    for (int dt = 0; dt < 8; dt++)
        *(f32x4*)(op + dt*16 + g*4) = Oa[dt];
    if (g == 0) {
        float* mlp = ml + (base + w*16 + c)*2;
        mlp[0] = mrun; mlp[1] = lrun;
    }
}

// grid (32, B), 256 thr
__global__ __launch_bounds__(256) void attn_reduce(const float* __restrict__ Opart,
        const float* __restrict__ ml, float* __restrict__ ao) {
    const int qt = blockIdx.x, b = blockIdx.y;
    const int tid = threadIdx.x;
    const int r = tid >> 2, qq = tid & 3;
    const int nch = (qt >> 1) + 1;
    const size_t base = ((size_t)b*32 + qt)*16;
    float M = -INFINITY;
    for (int i = 0; i < nch; i++) M = fmaxf(M, ml[(base+i)*128 + r*2]);
    float L = 0.f;
    for (int i = 0; i < nch; i++)
        L += ml[(base+i)*128 + r*2 + 1]*expf(ml[(base+i)*128 + r*2] - M);
    float o[32] = {};
    for (int i = 0; i < nch; i++) {
        float sc = expf(ml[(base+i)*128 + r*2] - M);
        const float* op = Opart + ((base+i)*64 + r)*DDIM + qq;
        #pragma unroll
        for (int m2 = 0; m2 < 32; m2++) o[m2] += sc*op[4*m2];
    }
    float linv = 1.0f / L;
    float* dst = ao + ((size_t)b*TSEQ + qt*64 + r)*DDIM + qq;
    #pragma unroll
    for (int m2 = 0; m2 < 32; m2++) dst[4*m2] = o[m2]*linv;
}

extern "C" void kernel_launch(void* const* d_in, const int* in_sizes, int n_in,
                              void* d_out, int out_size, void* d_ws, size_t ws_size,
                              hipStream_t stream) {
    const float* x     = (const float*)d_in[0];
    const int*   pos   = (const int*)d_in[1];
    const float* asim  = (const float*)d_in[2];
    const float* agate = (const float*)d_in[3];
    const float* qw    = (const float*)d_in[4];
    const float* kw    = (const float*)d_in[5];
    const float* vw    = (const float*)d_in[6];
    const float* ow    = (const float*)d_in[7];
    const float* msim  = (const float*)d_in[8];
    const float* mgate = (const float*)d_in[9];
    const float* w1    = (const float*)d_in[10];
    const float* w2    = (const float*)d_in[11];
    const int*   kqa   = (const int*)d_in[12];
    const int*   kqm   = (const int*)d_in[13];

    char* ws = (char*)d_ws;
    int*   counts_a = (int*)(ws + OFF_CA);
    int*   counts_m = (int*)(ws + OFF_CM);
    float* colinv   = (float*)(ws + OFF_CI);
    int*   offs_m   = (int*)(ws + OFF_OFFS);
    float* w_a      = (float*)(ws + OFF_WA);
    float* w_m      = (float*)(ws + OFF_WM);
    int*   list_a   = (int*)(ws + OFF_LA);
    int*   list_m   = (int*)(ws + OFF_LM);
    float* qb   = (float*)(ws + OFF_QB);
    float* kb   = (float*)(ws + OFF_KB);
    float* vb   = (float*)(ws + OFF_VB);
    float* ao   = (float*)(ws + OFF_AO);
    unsigned short* qhi = (unsigned short*)(ws + OFF_QHI);
    unsigned short* qlo = (unsigned short*)(ws + OFF_QLO);
    unsigned short* khi = (unsigned short*)(ws + OFF_KHI);
    unsigned short* klo = (unsigned short*)(ws + OFF_KLO);
    unsigned short* vTh = (unsigned short*)(ws + OFF_VTH);
    unsigned short* vTl = (unsigned short*)(ws + OFF_VTL);
    unsigned short* aobf = (unsigned short*)(ws + OFF_AOBF);
    float* mlb  = (float*)(ws + OFF_ML);
    unsigned short* wqt  = (unsigned short*)(ws + OFF_WQT);
    unsigned short* wkt  = (unsigned short*)(ws + OFF_WKT);
    unsigned short* wvt  = (unsigned short*)(ws + OFF_WVT);
    unsigned short* wot  = (unsigned short*)(ws + OFF_WOT);
    unsigned short* xbf  = (unsigned short*)(ws + OFF_XBF);
    unsigned short* hbf  = (unsigned short*)(ws + OFF_HBF);
    float* hb   = (float*)(ws + OFF_HB);
    unsigned short* Ab   = (unsigned short*)(ws + OFF_AB);
    float* Opart = (float*)(ws + OFF_OP);
    unsigned short* wxt  = (unsigned short*)(ws + OFF_WXT);
    float* out = (float*)d_out;

    (void)hipMemsetAsync(ws + OFF_CA, 0, 256, stream);
    (void)hipMemsetAsync(ws + OFF_QB, 0, MB(6), stream);     // qb,kb,vb

    colnorm_kernel<<<16, 256, 0, stream>>>(asim, msim, colinv);
    cvt_bf16<<<NT*CDIM/2048, 256, 0, stream>>>(x, xbf, NT*CDIM);

    transpose_cvt<<<dim3(2, 16, NE), 256, 0, stream>>>(qw, wqt, CDIM, DDIM);
    transpose_cvt<<<dim3(2, 16, NE), 256, 0, stream>>>(kw, wkt, CDIM, DDIM);
    transpose_cvt<<<dim3(2, 16, NE), 256, 0, stream>>>(vw, wvt, CDIM, DDIM);
    transpose_cvt<<<dim3(16, 2, NE), 256, 0, stream>>>(ow, wot, DDIM, CDIM);

    // ----- attention branch -----
    gating_kernel<<<NT, 256, 0, stream>>>(x, asim, agate, colinv, kqa, w_a, counts_a, list_a);
    ggemm<GM_QKV, CDIM, DDIM><<<dim3(NT/128, 3, NE), 256, 0, stream>>>(
        xbf, wqt, w_a, counts_a, list_a, nullptr, qb, kb, vb, nullptr);
    rope_cvt2<<<NT, 64, 0, stream>>>(qb, kb, pos, qhi, qlo, khi, klo);
    transpose_cvt2<<<dim3(2, 32, NB), 256, 0, stream>>>(vb, vTh, vTl, TSEQ, DDIM);
    attn_part<<<dim3(32, 16, NB), 256, 0, stream>>>(qhi, qlo, khi, klo, vTh, vTl, Opart, mlb);
    attn_reduce<<<dim3(32, NB), 256, 0, stream>>>(Opart, mlb, ao);
    cvt_bf16<<<NT*DDIM/2048, 256, 0, stream>>>(ao, aobf, NT*DDIM);

    (void)hipMemcpyAsync(hb, x, (size_t)NT*CDIM*4, hipMemcpyDeviceToDevice, stream);
    ggemm<GM_OPROJ, DDIM, CDIM><<<dim3(NT/128, 8, NE), 256, 0, stream>>>(
        aobf, wot, w_a, counts_a, list_a, nullptr, hb, nullptr, nullptr, nullptr);

    fuse_h<<<NT*CDIM/1024, 256, 0, stream>>>(hb, out, hbf);

    // ----- MoE branch -----
    gating_kernel<<<NT, 256, 0, stream>>>(hb, msim, mgate, colinv + NE, kqm, w_m, counts_m, list_m);
    scan_counts<<<1, 64, 0, stream>>>(counts_m, offs_m);
    // w1t into the (now dead) Opart region, then moe1; then w2t overwrites, then moe2.
    transpose_cvt<<<dim3(32, 16, NE), 256, 0, stream>>>(w1, wxt, CDIM, FFDIM);
    ggemm<GM_MOE1, CDIM, FFDIM><<<dim3(NT/128, 16, NE), 256, 0, stream>>>(
        hbf, wxt, w_m, counts_m, list_m, offs_m, nullptr, nullptr, nullptr, Ab);
    transpose_cvt<<<dim3(16, 32, NE), 256, 0, stream>>>(w2, wxt, FFDIM, CDIM);
    ggemm<GM_MOE2, FFDIM, CDIM><<<dim3(NT/128, 8, NE), 256, 0, stream>>>(
        Ab, wxt, w_m, counts_m, list_m, offs_m, out, nullptr, nullptr, nullptr);
}

// Round 6
// 713.800 us; speedup vs baseline: 5.8083x; 1.1854x over previous
//
#include <hip/hip_runtime.h>
#include <cstdint>

#define NB   2
#define TSEQ 2048
#define NT   4096
#define CDIM 1024
#define DDIM 128
#define FFDIM 2048
#define NE   8
#define ABCAP 8192

#define MB(x) ((size_t)(x) << 20)

// ---- workspace layout (121 MB total) ----
#define OFF_CA   ((size_t)0)
#define OFF_CM   ((size_t)64)
#define OFF_CI   ((size_t)128)
#define OFF_OFFS ((size_t)192)
#define OFF_WA   ((size_t)1024)
#define OFF_WM   (OFF_WA + (size_t)NT*NE*4)
#define OFF_LA   (OFF_WM + (size_t)NT*NE*4)
#define OFF_LM   (OFF_LA + (size_t)NT*NE*4)
#define OFF_QB   MB(1)
#define OFF_KB   MB(3)
#define OFF_VB   MB(5)
#define OFF_AO   MB(7)
#define OFF_QHI  MB(9)
#define OFF_QLO  MB(10)
#define OFF_KHI  MB(11)
#define OFF_KLO  MB(12)
#define OFF_VTH  MB(13)
#define OFF_VTL  MB(14)
#define OFF_AOBF MB(15)
#define OFF_ML   MB(16)
#define OFF_WQT  MB(17)
#define OFF_WKT  MB(19)
#define OFF_WVT  MB(21)
#define OFF_WOT  MB(23)
#define OFF_XBF  MB(25)
#define OFF_HBF  MB(33)
#define OFF_HB   MB(41)
#define OFF_AB   MB(57)
#define OFF_OP   MB(89)   // Opart (32MB) -> then w1t -> then w2t (sequential reuse)
#define OFF_WXT  MB(89)

typedef __attribute__((ext_vector_type(8))) short bf16x8;
typedef __attribute__((ext_vector_type(4))) float f32x4;

__device__ __forceinline__ float gelu_tanh(float x) {
    float x3 = x*x*x;
    return 0.5f*x*(1.0f + tanhf(0.79788456080286535588f*(x + 0.044715f*x3)));
}

__device__ __forceinline__ unsigned short f2bf(float f) {
    union { float f; uint32_t u; } v; v.f = f;
    uint32_t r = (v.u + 0x7fff + ((v.u >> 16) & 1)) >> 16;
    return (unsigned short)r;
}
__device__ __forceinline__ float bf2f(unsigned short h) {
    union { uint32_t u; float f; } v; v.u = ((uint32_t)h) << 16; return v.f;
}

// async global->LDS, 16B per lane; LDS dest = wave-uniform base + lane*16
__device__ __forceinline__ void gload16(const unsigned short* g, unsigned short* l) {
    __builtin_amdgcn_global_load_lds(
        (const __attribute__((address_space(1))) void*)g,
        (__attribute__((address_space(3))) void*)l,
        16, 0, 0);
}

// ---------------- fp32 -> bf16 ----------------
__global__ void cvt_bf16(const float* __restrict__ in, unsigned short* __restrict__ out, int n) {
    int i = (blockIdx.x*256 + threadIdx.x)*8;
    if (i >= n) return;
    float4 a = *(const float4*)(in + i);
    float4 b = *(const float4*)(in + i + 4);
    unsigned short t[8] = {f2bf(a.x), f2bf(a.y), f2bf(a.z), f2bf(a.w),
                           f2bf(b.x), f2bf(b.y), f2bf(b.z), f2bf(b.w)};
    *(uint4*)(out + i) = *(uint4*)t;
}

// ---------------- fused: out=h (fp32) + hbf (bf16) ----------------
__global__ void fuse_h(const float* __restrict__ hb, float* __restrict__ out,
                       unsigned short* __restrict__ hbf) {
    int i = (blockIdx.x*256 + threadIdx.x)*4;
    float4 v = *(const float4*)(hb + i);
    *(float4*)(out + i) = v;
    unsigned short t[4] = {f2bf(v.x), f2bf(v.y), f2bf(v.z), f2bf(v.w)};
    *(uint2*)(hbf + i) = *(uint2*)t;
}

// ---------------- transpose + convert: fp32 [R][C] -> bf16 [C][R] ----------------
__global__ __launch_bounds__(256) void transpose_cvt(const float* __restrict__ in,
        unsigned short* __restrict__ out, int R, int C) {
    const float* inp = in + (size_t)blockIdx.z*R*C;
    unsigned short* outp = out + (size_t)blockIdx.z*R*C;
    int rb = blockIdx.y*64, cb = blockIdx.x*64;
    __shared__ unsigned short T[64][65];
    int tid = threadIdx.x;
    int lr = tid >> 2, lc0 = (tid & 3)*16;
    const float* src = inp + (size_t)(rb + lr)*C + cb + lc0;
    #pragma unroll
    for (int i = 0; i < 16; i += 4) {
        float4 f = *(const float4*)(src + i);
        T[lr][lc0+i+0] = f2bf(f.x); T[lr][lc0+i+1] = f2bf(f.y);
        T[lr][lc0+i+2] = f2bf(f.z); T[lr][lc0+i+3] = f2bf(f.w);
    }
    __syncthreads();
    int oc = tid >> 2, or0 = (tid & 3)*16;
    unsigned short tmp[16];
    #pragma unroll
    for (int i = 0; i < 16; i++) tmp[i] = T[or0+i][oc];
    *(uint4*)(outp + (size_t)(cb+oc)*R + rb + or0)     = *(uint4*)&tmp[0];
    *(uint4*)(outp + (size_t)(cb+oc)*R + rb + or0 + 8) = *(uint4*)&tmp[8];
}

// ---------------- transpose + hi/lo split convert ----------------
__global__ __launch_bounds__(256) void transpose_cvt2(const float* __restrict__ in,
        unsigned short* __restrict__ outh, unsigned short* __restrict__ outl, int R, int C) {
    const float* inp = in + (size_t)blockIdx.z*R*C;
    unsigned short* oph = outh + (size_t)blockIdx.z*R*C;
    unsigned short* opl = outl + (size_t)blockIdx.z*R*C;
    int rb = blockIdx.y*64, cb = blockIdx.x*64;
    __shared__ unsigned short Th[64][65];
    __shared__ unsigned short Tl[64][65];
    int tid = threadIdx.x;
    int lr = tid >> 2, lc0 = (tid & 3)*16;
    const float* src = inp + (size_t)(rb + lr)*C + cb + lc0;
    #pragma unroll
    for (int i = 0; i < 16; i += 4) {
        float4 f = *(const float4*)(src + i);
        float fa[4] = {f.x, f.y, f.z, f.w};
        #pragma unroll
        for (int jj = 0; jj < 4; jj++) {
            unsigned short h = f2bf(fa[jj]);
            Th[lr][lc0+i+jj] = h;
            Tl[lr][lc0+i+jj] = f2bf(fa[jj] - bf2f(h));
        }
    }
    __syncthreads();
    int oc = tid >> 2, or0 = (tid & 3)*16;
    unsigned short th[16], tl[16];
    #pragma unroll
    for (int i = 0; i < 16; i++) { th[i] = Th[or0+i][oc]; tl[i] = Tl[or0+i][oc]; }
    size_t o = (size_t)(cb+oc)*R + rb + or0;
    *(uint4*)(oph + o)     = *(uint4*)&th[0];
    *(uint4*)(oph + o + 8) = *(uint4*)&th[8];
    *(uint4*)(opl + o)     = *(uint4*)&tl[0];
    *(uint4*)(opl + o + 8) = *(uint4*)&tl[8];
}

// ---------------- column norms ----------------
__global__ void colnorm_kernel(const float* __restrict__ asim,
                               const float* __restrict__ msim,
                               float* __restrict__ inv) {
    int col = blockIdx.x;
    const float* s = (col < NE) ? asim : msim;
    int e = col & (NE-1);
    int tid = threadIdx.x;
    float ss = 0.0f;
    for (int c = tid; c < CDIM; c += 256) { float v = s[(size_t)c*NE + e]; ss += v*v; }
    __shared__ float red[256];
    red[tid] = ss; __syncthreads();
    for (int st = 128; st > 0; st >>= 1) { if (tid < st) red[tid] += red[tid+st]; __syncthreads(); }
    if (tid == 0) inv[col] = 1.0f / fmaxf(sqrtf(red[0]), 1e-12f);
}

// ---------------- gating (proven tree-reduction version) ----------------
__global__ void gating_kernel(const float* __restrict__ xin,
                              const float* __restrict__ sim,
                              const float* __restrict__ gates,
                              const float* __restrict__ colinv,
                              const int* __restrict__ kmin_p,
                              float* __restrict__ wout,
                              int* __restrict__ counts,
                              int* __restrict__ lists) {
    const int n = blockIdx.x, tid = threadIdx.x;
    const float* xr = xin + (size_t)n*CDIM;
    float4 xv = *(const float4*)(xr + tid*4);
    float acc[9];
    acc[0] = xv.x*xv.x + xv.y*xv.y + xv.z*xv.z + xv.w*xv.w;
    int c = tid*4;
    #pragma unroll
    for (int e = 0; e < NE; e++)
        acc[1+e] = xv.x*sim[(size_t)(c+0)*NE+e] + xv.y*sim[(size_t)(c+1)*NE+e]
                 + xv.z*sim[(size_t)(c+2)*NE+e] + xv.w*sim[(size_t)(c+3)*NE+e];
    __shared__ float red[9][256];
    #pragma unroll
    for (int a = 0; a < 9; a++) red[a][tid] = acc[a];
    __syncthreads();
    for (int s = 128; s > 0; s >>= 1) {
        if (tid < s) {
            #pragma unroll
            for (int a = 0; a < 9; a++) red[a][tid] += red[a][tid+s];
        }
        __syncthreads();
    }
    if (tid == 0) {
        float xinv = 1.0f / fmaxf(sqrtf(red[0][0]), 1e-12f);
        float logits[NE], gated[NE];
        int mask[NE]; int any = 0;
        #pragma unroll
        for (int e = 0; e < NE; e++) {
            float lg = red[1+e][0]*xinv*colinv[e] - 1.0f/(1.0f + expf(-gates[e]));
            logits[e] = lg; gated[e] = fmaxf(lg, 0.0f);
            mask[e] = (lg > 0.0f) ? 1 : 0; any |= mask[e];
        }
        if (!any) {
            int kmin = *kmin_p; if (kmin < 1) kmin = 1; if (kmin > NE) kmin = NE;
            int used[NE] = {0,0,0,0,0,0,0,0};
            for (int kk = 0; kk < kmin; kk++) {
                int best = -1; float bv = 0.0f;
                for (int e = 0; e < NE; e++)
                    if (!used[e] && (best < 0 || logits[e] > bv)) { best = e; bv = logits[e]; }
                used[best] = 1; mask[best] = 1;
            }
        }
        float mx = -3.402823466e38f;
        #pragma unroll
        for (int e = 0; e < NE; e++) { float me = mask[e] ? gated[e] : -1.0e9f; mx = fmaxf(mx, me); }
        float sum = 0.0f, p[NE];
        #pragma unroll
        for (int e = 0; e < NE; e++) { p[e] = expf((mask[e] ? gated[e] : -1.0e9f) - mx); sum += p[e]; }
        float sinv = 1.0f / sum;
        #pragma unroll
        for (int e = 0; e < NE; e++) {
            float w = mask[e] ? p[e]*sinv : 0.0f;
            wout[(size_t)n*NE + e] = w;
            if (mask[e]) { int pos = atomicAdd(&counts[e], 1); lists[e*NT + pos] = n; }
        }
    }
}

__global__ void scan_counts(const int* __restrict__ counts, int* __restrict__ offs) {
    if (threadIdx.x == 0) {
        int s = 0;
        for (int e = 0; e < NE; e++) { offs[e] = s; s += counts[e]; }
    }
}

// ---------------- grouped bf16 MFMA GEMM, m97-style pipeline ----------------
// 128x128 tile, BK=64, double-buffered LDS via global_load_lds(16B) with
// pre-swizzled global source (slot ^= row&7); XOR-swizzled ds_read_b128 hits
// the 8-cycle wave64 minimum (all 8 bank-quads, 2 lanes each).
#define GM_QKV   0
#define GM_OPROJ 1
#define GM_MOE1  2
#define GM_MOE2  3

template<int MODE, int K, int N>
__global__ __launch_bounds__(256) void ggemm(
        const unsigned short* __restrict__ Abase,
        const unsigned short* __restrict__ Bt_,     // bf16 [e][N][K]
        const float* __restrict__ wgt_,
        const int* __restrict__ counts_,
        const int* __restrict__ lists_,
        const int* __restrict__ offs_,
        float* __restrict__ d0, float* __restrict__ d1, float* __restrict__ d2,
        unsigned short* __restrict__ du) {
    const int e = blockIdx.z;
    const int cnt = counts_[e];
    const int tm = blockIdx.x;
    if (tm*128 >= cnt) return;
    int n0 = 0, kbeg = 0, kspan = K;
    const unsigned short* Bt = Bt_;
    float* dst = d0;
    if constexpr (MODE == GM_QKV) {
        int proj = blockIdx.y >> 1;            // 0,1,2 = q,k,v
        kbeg = (blockIdx.y & 1)*(K/2); kspan = K/2;   // split-K x2
        Bt = Bt_ + (size_t)proj*((size_t)NE*N*K);
        dst = (proj == 0) ? d0 : (proj == 1) ? d1 : d2;
    } else {
        n0 = blockIdx.y*128;
    }
    const int eoff = (MODE == GM_MOE1 || MODE == GM_MOE2) ? offs_[e] : 0;
    const unsigned short* Bexp = Bt + (size_t)e*N*K + (size_t)n0*K;

    __shared__ unsigned short As[2][128][64];   // 32 KB
    __shared__ unsigned short Bs[2][128][64];   // 32 KB
    __shared__ int   toks[128];
    __shared__ float wro[128];
    const int tid = threadIdx.x;
    for (int i = tid; i < 128; i += 256) {
        int rid = tm*128 + i;
        int t = lists_[e*NT + (rid < cnt ? rid : cnt-1)];
        toks[i] = t;
        wro[i] = wgt_[(size_t)t*NE + e];
    }
    __syncthreads();

    const int lane = tid & 63, wid = tid >> 6;
    const int wr = wid >> 1, wc = wid & 1;
    const int fr = lane & 15, ks = lane >> 4;
    const int lrow8 = lane >> 3, slot = lane & 7;
    const int sl = slot ^ lrow8;                 // swizzled source slot (const per lane)

    // precompute per-lane global row pointers (incl. swizzled slot offset)
    const unsigned short* arow[4];
    const unsigned short* brow[4];
    #pragma unroll
    for (int i = 0; i < 4; i++) {
        int r = wid*32 + i*8 + lrow8;
        if constexpr (MODE == GM_MOE2) {
            int pos = tm*128 + r; if (pos >= cnt) pos = cnt - 1;
            int rowg = eoff + pos; if (rowg > ABCAP-1) rowg = ABCAP-1;
            arow[i] = Abase + (size_t)rowg*K + sl*8;
        } else {
            arow[i] = Abase + (size_t)toks[r]*K + sl*8;
        }
        brow[i] = Bexp + (size_t)r*K + sl*8;
    }

    f32x4 acc[4][4];
    #pragma unroll
    for (int i = 0; i < 4; i++)
        #pragma unroll
        for (int j = 0; j < 4; j++) acc[i][j] = (f32x4){0.f, 0.f, 0.f, 0.f};

    const int nst = kspan/64;
    // prologue
    #pragma unroll
    for (int i = 0; i < 4; i++) {
        gload16(arow[i] + kbeg, &As[0][wid*32 + i*8][0]);
        gload16(brow[i] + kbeg, &Bs[0][wid*32 + i*8][0]);
    }
    asm volatile("s_waitcnt vmcnt(0)" ::: "memory");
    __syncthreads();

    int cur = 0;
    for (int t = 0; t < nst; t++) {
        if (t + 1 < nst) {
            int k0 = kbeg + (t+1)*64;
            #pragma unroll
            for (int i = 0; i < 4; i++) {
                gload16(arow[i] + k0, &As[cur^1][wid*32 + i*8][0]);
                gload16(brow[i] + k0, &Bs[cur^1][wid*32 + i*8][0]);
            }
        }
        __builtin_amdgcn_sched_barrier(0);      // keep load issue ahead of compute
        #pragma unroll
        for (int kk = 0; kk < 2; kk++) {
            bf16x8 af[4], bg[4];
            #pragma unroll
            for (int m = 0; m < 4; m++) {
                int rA = wr*64 + m*16 + fr;
                af[m] = *(const bf16x8*)&As[cur][rA][(((kk*4 + ks) ^ (rA & 7)))*8];
            }
            #pragma unroll
            for (int n = 0; n < 4; n++) {
                int rB = wc*64 + n*16 + fr;
                bg[n] = *(const bf16x8*)&Bs[cur][rB][(((kk*4 + ks) ^ (rB & 7)))*8];
            }
            #pragma unroll
            for (int m = 0; m < 4; m++)
                #pragma unroll
                for (int n = 0; n < 4; n++)
                    acc[m][n] = __builtin_amdgcn_mfma_f32_16x16x32_bf16(af[m], bg[n], acc[m][n], 0, 0, 0);
        }
        asm volatile("s_waitcnt vmcnt(0)" ::: "memory");
        __syncthreads();
        cur ^= 1;
    }

    #pragma unroll
    for (int m = 0; m < 4; m++) {
        #pragma unroll
        for (int rg = 0; rg < 4; rg++) {
            int lr = wr*64 + m*16 + ks*4 + rg;
            if (tm*128 + lr >= cnt) continue;
            int t = toks[lr]; float wv = wro[lr];
            #pragma unroll
            for (int n = 0; n < 4; n++) {
                int gc = n0 + wc*64 + n*16 + fr;
                float v = acc[m][n][rg];
                if constexpr (MODE == GM_QKV)
                    atomicAdd(dst + (size_t)t*DDIM + gc, v*wv);
                else if constexpr (MODE == GM_OPROJ)
                    atomicAdd(dst + (size_t)t*CDIM + gc, v*wv);
                else if constexpr (MODE == GM_MOE1) {
                    int row = eoff + tm*128 + lr;
                    if (row < ABCAP)
                        du[(size_t)row*FFDIM + gc] = f2bf(gelu_tanh(v));
                } else
                    atomicAdd(dst + (size_t)t*CDIM + gc, v*wv);
            }
        }
    }
}

// ---------------- RoPE + hi/lo bf16 split ----------------
__global__ void rope_cvt2(const float* __restrict__ q, const float* __restrict__ k,
        const int* __restrict__ pos_ids,
        unsigned short* __restrict__ qh, unsigned short* __restrict__ ql,
        unsigned short* __restrict__ kh, unsigned short* __restrict__ kl) {
    int n = blockIdx.x, j = threadIdx.x;   // j in 0..63
    float pos = (float)pos_ids[n];
    float inv = expf(-((float)j / 64.0f) * 9.21034037197618274f);
    float ang = pos * inv;
    float c = cosf(ang), s = sinf(ang);
    const float* qr = q + (size_t)n*DDIM;
    const float* kr = k + (size_t)n*DDIM;
    size_t base = (size_t)n*DDIM;
    float v0 = qr[j], v1 = qr[j+64];
    float a = v0*c - v1*s, b2 = v1*c + v0*s;
    unsigned short h;
    h = f2bf(a);  qh[base+j]    = h; ql[base+j]    = f2bf(a  - bf2f(h));
    h = f2bf(b2); qh[base+j+64] = h; ql[base+j+64] = f2bf(b2 - bf2f(h));
    v0 = kr[j]; v1 = kr[j+64];
    a = v0*c - v1*s; b2 = v1*c + v0*s;
    h = f2bf(a);  kh[base+j]    = h; kl[base+j]    = f2bf(a  - bf2f(h));
    h = f2bf(b2); kh[base+j+64] = h; kl[base+j+64] = f2bf(b2 - bf2f(h));
}

// ---------------- split-precision MFMA split-KV flash attention ----------------
__global__ __launch_bounds__(256) void attn_part(
        const unsigned short* __restrict__ qh_, const unsigned short* __restrict__ ql_,
        const unsigned short* __restrict__ kh_, const unsigned short* __restrict__ kl_,
        const unsigned short* __restrict__ vTh, const unsigned short* __restrict__ vTl,
        float* __restrict__ Opart, float* __restrict__ ml) {
    const int qt = blockIdx.x, ch = blockIdx.y, b = blockIdx.z;
    const int qmax = qt*64 + 63;
    if (ch*128 > qmax) return;
    const int tid = threadIdx.x;
    const int w = tid >> 6, lane = tid & 63;
    const int c = lane & 15, g = lane >> 4;
    const int qrow = qt*64 + w*16 + c;
    const float scale = 0.08838834764831845f;

    __shared__ unsigned short Ph[4][16][72];
    __shared__ unsigned short Pl[4][16][72];

    bf16x8 qfh[4], qfl[4];
    const size_t qoff = ((size_t)b*TSEQ + qrow)*DDIM;
    #pragma unroll
    for (int ds = 0; ds < 4; ds++) {
        qfh[ds] = *(const bf16x8*)(qh_ + qoff + ds*32 + g*8);
        qfl[ds] = *(const bf16x8*)(ql_ + qoff + ds*32 + g*8);
    }

    f32x4 Oa[8];
    #pragma unroll
    for (int i = 0; i < 8; i++) Oa[i] = (f32x4){0.f, 0.f, 0.f, 0.f};
    float mrun = -INFINITY, lrun = 0.f;

    for (int t = 0; t < 2; t++) {
        const int kv0 = ch*128 + t*64;
        if (kv0 > qmax) break;
        f32x4 Sa[4];
        #pragma unroll
        for (int m = 0; m < 4; m++) Sa[m] = (f32x4){0.f, 0.f, 0.f, 0.f};
        #pragma unroll
        for (int ds = 0; ds < 4; ds++) {
            #pragma unroll
            for (int m = 0; m < 4; m++) {
                const size_t ko = ((size_t)b*TSEQ + kv0 + m*16 + c)*DDIM + ds*32 + g*8;
                bf16x8 kfh = *(const bf16x8*)(kh_ + ko);
                bf16x8 kfl = *(const bf16x8*)(kl_ + ko);
                Sa[m] = __builtin_amdgcn_mfma_f32_16x16x32_bf16(kfh, qfh[ds], Sa[m], 0, 0, 0);
                Sa[m] = __builtin_amdgcn_mfma_f32_16x16x32_bf16(kfh, qfl[ds], Sa[m], 0, 0, 0);
                Sa[m] = __builtin_amdgcn_mfma_f32_16x16x32_bf16(kfl, qfh[ds], Sa[m], 0, 0, 0);
            }
        }
        float sv[16]; float mloc = -INFINITY;
        #pragma unroll
        for (int m = 0; m < 4; m++)
            #pragma unroll
            for (int r = 0; r < 4; r++) {
                int kv = kv0 + m*16 + g*4 + r;
                float s = Sa[m][r]*scale;
                if (kv > qrow) s = -3.0e38f;
                sv[m*4+r] = s;
                mloc = fmaxf(mloc, s);
            }
        mloc = fmaxf(mloc, __shfl_xor(mloc, 16));
        mloc = fmaxf(mloc, __shfl_xor(mloc, 32));
        float mnew = fmaxf(fmaxf(mrun, mloc), -1.0e30f);
        float alpha = expf(mrun - mnew);
        float ls = 0.f;
        #pragma unroll
        for (int i = 0; i < 16; i++) { sv[i] = expf(sv[i] - mnew); ls += sv[i]; }
        ls += __shfl_xor(ls, 16); ls += __shfl_xor(ls, 32);
        lrun = lrun*alpha + ls; mrun = mnew;
        #pragma unroll
        for (int i = 0; i < 8; i++) Oa[i] *= alpha;
        #pragma unroll
        for (int m = 0; m < 4; m++) {
            unsigned short h0 = f2bf(sv[m*4+0]), h1 = f2bf(sv[m*4+1]);
            unsigned short h2 = f2bf(sv[m*4+2]), h3 = f2bf(sv[m*4+3]);
            unsigned int* ph = (unsigned int*)&Ph[w][c][m*16 + g*4];
            ph[0] = (unsigned int)h0 | ((unsigned int)h1 << 16);
            ph[1] = (unsigned int)h2 | ((unsigned int)h3 << 16);
            unsigned short l0 = f2bf(sv[m*4+0] - bf2f(h0)), l1 = f2bf(sv[m*4+1] - bf2f(h1));
            unsigned short l2 = f2bf(sv[m*4+2] - bf2f(h2)), l3 = f2bf(sv[m*4+3] - bf2f(h3));
            unsigned int* pl = (unsigned int*)&Pl[w][c][m*16 + g*4];
            pl[0] = (unsigned int)l0 | ((unsigned int)l1 << 16);
            pl[1] = (unsigned int)l2 | ((unsigned int)l3 << 16);
        }
        #pragma unroll
        for (int ksx = 0; ksx < 2; ksx++) {
            bf16x8 pfh = *(const bf16x8*)&Ph[w][c][ksx*32 + g*8];
            bf16x8 pfl = *(const bf16x8*)&Pl[w][c][ksx*32 + g*8];
            #pragma unroll
            for (int dt = 0; dt < 8; dt++) {
                const size_t vo = ((size_t)b*DDIM + c + dt*16)*TSEQ + kv0 + ksx*32 + g*8;
                bf16x8 vfh = *(const bf16x8*)(vTh + vo);
                bf16x8 vfl = *(const bf16x8*)(vTl + vo);
                Oa[dt] = __builtin_amdgcn_mfma_f32_16x16x32_bf16(vfh, pfh, Oa[dt], 0, 0, 0);
                Oa[dt] = __builtin_amdgcn_mfma_f32_16x16x32_bf16(vfh, pfl, Oa[dt], 0, 0, 0);
                Oa[dt] = __builtin_amdgcn_mfma_f32_16x16x32_bf16(vfl, pfh, Oa[dt], 0, 0, 0);
            }
        }
    }
    const size_t base = (((size_t)b*32 + qt)*16 + ch)*64;
    float* op = Opart + (base + w*16 + c)*DDIM;
    #pragma unroll
    for (int dt = 0; dt < 8; dt++)
        *(f32x4*)(op + dt*16 + g*4) = Oa[dt];
    if (g == 0) {
        float* mlp = ml + (base + w*16 + c)*2;
        mlp[0] = mrun; mlp[1] = lrun;
    }
}

// grid (32, B), 256 thr
__global__ __launch_bounds__(256) void attn_reduce(const float* __restrict__ Opart,
        const float* __restrict__ ml, float* __restrict__ ao) {
    const int qt = blockIdx.x, b = blockIdx.y;
    const int tid = threadIdx.x;
    const int r = tid >> 2, qq = tid & 3;
    const int nch = (qt >> 1) + 1;
    const size_t base = ((size_t)b*32 + qt)*16;
    float M = -INFINITY;
    for (int i = 0; i < nch; i++) M = fmaxf(M, ml[(base+i)*128 + r*2]);
    float L = 0.f;
    for (int i = 0; i < nch; i++)
        L += ml[(base+i)*128 + r*2 + 1]*expf(ml[(base+i)*128 + r*2] - M);
    float o[32] = {};
    for (int i = 0; i < nch; i++) {
        float sc = expf(ml[(base+i)*128 + r*2] - M);
        const float* op = Opart + ((base+i)*64 + r)*DDIM + qq;
        #pragma unroll
        for (int m2 = 0; m2 < 32; m2++) o[m2] += sc*op[4*m2];
    }
    float linv = 1.0f / L;
    float* dst = ao + ((size_t)b*TSEQ + qt*64 + r)*DDIM + qq;
    #pragma unroll
    for (int m2 = 0; m2 < 32; m2++) dst[4*m2] = o[m2]*linv;
}

extern "C" void kernel_launch(void* const* d_in, const int* in_sizes, int n_in,
                              void* d_out, int out_size, void* d_ws, size_t ws_size,
                              hipStream_t stream) {
    const float* x     = (const float*)d_in[0];
    const int*   pos   = (const int*)d_in[1];
    const float* asim  = (const float*)d_in[2];
    const float* agate = (const float*)d_in[3];
    const float* qw    = (const float*)d_in[4];
    const float* kw    = (const float*)d_in[5];
    const float* vw    = (const float*)d_in[6];
    const float* ow    = (const float*)d_in[7];
    const float* msim  = (const float*)d_in[8];
    const float* mgate = (const float*)d_in[9];
    const float* w1    = (const float*)d_in[10];
    const float* w2    = (const float*)d_in[11];
    const int*   kqa   = (const int*)d_in[12];
    const int*   kqm   = (const int*)d_in[13];

    char* ws = (char*)d_ws;
    int*   counts_a = (int*)(ws + OFF_CA);
    int*   counts_m = (int*)(ws + OFF_CM);
    float* colinv   = (float*)(ws + OFF_CI);
    int*   offs_m   = (int*)(ws + OFF_OFFS);
    float* w_a      = (float*)(ws + OFF_WA);
    float* w_m      = (float*)(ws + OFF_WM);
    int*   list_a   = (int*)(ws + OFF_LA);
    int*   list_m   = (int*)(ws + OFF_LM);
    float* qb   = (float*)(ws + OFF_QB);
    float* kb   = (float*)(ws + OFF_KB);
    float* vb   = (float*)(ws + OFF_VB);
    float* ao   = (float*)(ws + OFF_AO);
    unsigned short* qhi = (unsigned short*)(ws + OFF_QHI);
    unsigned short* qlo = (unsigned short*)(ws + OFF_QLO);
    unsigned short* khi = (unsigned short*)(ws + OFF_KHI);
    unsigned short* klo = (unsigned short*)(ws + OFF_KLO);
    unsigned short* vTh = (unsigned short*)(ws + OFF_VTH);
    unsigned short* vTl = (unsigned short*)(ws + OFF_VTL);
    unsigned short* aobf = (unsigned short*)(ws + OFF_AOBF);
    float* mlb  = (float*)(ws + OFF_ML);
    unsigned short* wqt  = (unsigned short*)(ws + OFF_WQT);
    unsigned short* wkt  = (unsigned short*)(ws + OFF_WKT);
    unsigned short* wvt  = (unsigned short*)(ws + OFF_WVT);
    unsigned short* wot  = (unsigned short*)(ws + OFF_WOT);
    unsigned short* xbf  = (unsigned short*)(ws + OFF_XBF);
    unsigned short* hbf  = (unsigned short*)(ws + OFF_HBF);
    float* hb   = (float*)(ws + OFF_HB);
    unsigned short* Ab   = (unsigned short*)(ws + OFF_AB);
    float* Opart = (float*)(ws + OFF_OP);
    unsigned short* wxt  = (unsigned short*)(ws + OFF_WXT);
    float* out = (float*)d_out;

    (void)hipMemsetAsync(ws + OFF_CA, 0, 256, stream);
    (void)hipMemsetAsync(ws + OFF_QB, 0, MB(6), stream);     // qb,kb,vb

    colnorm_kernel<<<16, 256, 0, stream>>>(asim, msim, colinv);
    cvt_bf16<<<NT*CDIM/2048, 256, 0, stream>>>(x, xbf, NT*CDIM);

    transpose_cvt<<<dim3(2, 16, NE), 256, 0, stream>>>(qw, wqt, CDIM, DDIM);
    transpose_cvt<<<dim3(2, 16, NE), 256, 0, stream>>>(kw, wkt, CDIM, DDIM);
    transpose_cvt<<<dim3(2, 16, NE), 256, 0, stream>>>(vw, wvt, CDIM, DDIM);
    transpose_cvt<<<dim3(16, 2, NE), 256, 0, stream>>>(ow, wot, DDIM, CDIM);

    // ----- attention branch -----
    gating_kernel<<<NT, 256, 0, stream>>>(x, asim, agate, colinv, kqa, w_a, counts_a, list_a);
    ggemm<GM_QKV, CDIM, DDIM><<<dim3(NT/128, 6, NE), 256, 0, stream>>>(
        xbf, wqt, w_a, counts_a, list_a, nullptr, qb, kb, vb, nullptr);
    rope_cvt2<<<NT, 64, 0, stream>>>(qb, kb, pos, qhi, qlo, khi, klo);
    transpose_cvt2<<<dim3(2, 32, NB), 256, 0, stream>>>(vb, vTh, vTl, TSEQ, DDIM);
    attn_part<<<dim3(32, 16, NB), 256, 0, stream>>>(qhi, qlo, khi, klo, vTh, vTl, Opart, mlb);
    attn_reduce<<<dim3(32, NB), 256, 0, stream>>>(Opart, mlb, ao);
    cvt_bf16<<<NT*DDIM/2048, 256, 0, stream>>>(ao, aobf, NT*DDIM);

    (void)hipMemcpyAsync(hb, x, (size_t)NT*CDIM*4, hipMemcpyDeviceToDevice, stream);
    ggemm<GM_OPROJ, DDIM, CDIM><<<dim3(NT/128, 8, NE), 256, 0, stream>>>(
        aobf, wot, w_a, counts_a, list_a, nullptr, hb, nullptr, nullptr, nullptr);

    fuse_h<<<NT*CDIM/1024, 256, 0, stream>>>(hb, out, hbf);

    // ----- MoE branch -----
    gating_kernel<<<NT, 256, 0, stream>>>(hb, msim, mgate, colinv + NE, kqm, w_m, counts_m, list_m);
    scan_counts<<<1, 64, 0, stream>>>(counts_m, offs_m);
    transpose_cvt<<<dim3(32, 16, NE), 256, 0, stream>>>(w1, wxt, CDIM, FFDIM);
    ggemm<GM_MOE1, CDIM, FFDIM><<<dim3(NT/128, 16, NE), 256, 0, stream>>>(
        hbf, wxt, w_m, counts_m, list_m, offs_m, nullptr, nullptr, nullptr, Ab);
    transpose_cvt<<<dim3(16, 32, NE), 256, 0, stream>>>(w2, wxt, FFDIM, CDIM);
    ggemm<GM_MOE2, FFDIM, CDIM><<<dim3(NT/128, 8, NE), 256, 0, stream>>>(
        Ab, wxt, w_m, counts_m, list_m, offs_m, out, nullptr, nullptr, nullptr);
}